// Round 28
// baseline (261.126 us; speedup 1.0000x reference)
//
#include <hip/hip_runtime.h>
#include <hip/hip_bf16.h>

#define IN_DIM 128
#define HID    64
#define NH     4
#define F1     256   // NH*HID
#define OUTD   64
#define NEG    0.2f
#define LOG2E  1.44269504088896f

#define EXP2F(x) __builtin_amdgcn_exp2f(x)

typedef __attribute__((ext_vector_type(8))) short bf16x8;
typedef __attribute__((ext_vector_type(4))) float f32x4;

__device__ __forceinline__ float bf2f(unsigned short h) {
  return __uint_as_float((unsigned)h << 16);
}
__device__ __forceinline__ unsigned short f2bf(float f) {
  unsigned u = __float_as_uint(f);
  u += 0x7fffu + ((u >> 16) & 1u);   // RTNE
  return (unsigned short)(u >> 16);
}
__device__ __forceinline__ bf16x8 f2bf8(const float* p) {
  float4 lo = *(const float4*)p;
  float4 hi = *(const float4*)(p + 4);
  bf16x8 r;
  r[0] = (short)f2bf(lo.x); r[1] = (short)f2bf(lo.y);
  r[2] = (short)f2bf(lo.z); r[3] = (short)f2bf(lo.w);
  r[4] = (short)f2bf(hi.x); r[5] = (short)f2bf(hi.y);
  r[6] = (short)f2bf(hi.z); r[7] = (short)f2bf(hi.w);
  return r;
}

// ---------------- fused conversions: x->bf16, weights, cnt4 zero ------------
__global__ __launch_bounds__(256) void k_cvt_all(
    const float* __restrict__ x, unsigned short* __restrict__ xb, int NX8,
    const float* __restrict__ W1l, const float* __restrict__ W1r,
    const float* __restrict__ W2l, const float* __restrict__ W2r,
    const float* __restrict__ Wm1,
    unsigned short* __restrict__ Wt, unsigned short* __restrict__ Wt2,
    unsigned short* __restrict__ Wuv, int* __restrict__ cnt4, int N) {
  int idx = blockIdx.x * 256 + threadIdx.x;
  if (idx < NX8) {
    bf16x8 r = f2bf8(x + (size_t)idx * 8);
    *(bf16x8*)(xb + (size_t)idx * 8) = r;
    return;
  }
  int j0 = idx - NX8;
  if (j0 < 4 * N) cnt4[j0] = 0;
  if (j0 < 512 * IN_DIM) {
    int c = j0 >> 7, k = j0 & 127;
    float v = (c < F1) ? W1l[k * F1 + c] : W1r[k * F1 + (c - F1)];
    Wt[j0] = f2bf(v);
  } else if (j0 < 512 * IN_DIM + 128 * F1) {
    int j = j0 - 512 * IN_DIM;
    int c = j >> 8, k = j & 255;
    float v = (c < OUTD) ? W2l[k * OUTD + c] : W2r[k * OUTD + (c - OUTD)];
    Wt2[j] = f2bf(v);
  } else if (j0 < 512 * IN_DIM + 128 * F1 + 128 * OUTD) {
    int j = j0 - 512 * IN_DIM - 128 * F1;
    int c = j >> 6, k = j & 63;
    float v = (c < OUTD) ? Wm1[k * OUTD + c] : Wm1[(64 + k) * OUTD + (c - OUTD)];
    Wuv[j] = f2bf(v);
  }
}

// ---------------- layer-1 GEMM via MFMA + y-privatized rank-hist ------------
// grid ((N+63)/64, 4). Copy = blockIdx.y: contention per cache line / 4.
__global__ __launch_bounds__(256) void k_gemm1_mfma(
    const unsigned short* __restrict__ xb, const unsigned short* __restrict__ Wt,
    const float* __restrict__ bl, const float* __restrict__ br,
    unsigned short* __restrict__ xlh, unsigned short* __restrict__ xrh,
    const int* __restrict__ ei, int E, int* __restrict__ cnt4,
    int* __restrict__ rank, int N) {
  int tid = threadIdx.x, lane = tid & 63, w = tid >> 6;
  int node0 = blockIdx.x * 64 + w * 16;
  int colbase = blockIdx.y * 128;
  int l16 = lane & 15, khi = lane >> 4;
  int koff = khi * 8;
  int arow = node0 + l16; if (arow >= N) arow = N - 1;
  const unsigned short* ap = xb + (size_t)arow * IN_DIM + koff;
  bf16x8 b0 = *(const bf16x8*)(ap);
  bf16x8 b1 = *(const bf16x8*)(ap + 32);
  bf16x8 b2 = *(const bf16x8*)(ap + 64);
  bf16x8 b3 = *(const bf16x8*)(ap + 96);
  // fused histogram: 1 edge/thread into the y-private copy
  {
    int gid = blockIdx.y * gridDim.x + blockIdx.x;
    int e = gid * 256 + tid;
    if (e < E) {
      int d = ei[E + e];
      rank[e] = atomicAdd(&cnt4[blockIdx.y * N + d], 1);
    }
  }
  int node = node0 + l16;
  bool nok = node < N;
  bool isL = (colbase < F1);
  unsigned short* dst = isL ? xlh : xrh;
  const float* bias = isL ? bl : br;
  int cofs = isL ? colbase : (colbase - F1);
#pragma unroll
  for (int cp = 0; cp < 4; cp++) {
    int ct0 = cp * 2, ct1 = cp * 2 + 1;
    const unsigned short* wp0 = Wt + (size_t)(colbase + ct0 * 16 + l16) * IN_DIM + koff;
    const unsigned short* wp1 = Wt + (size_t)(colbase + ct1 * 16 + l16) * IN_DIM + koff;
    f32x4 a0 = {0.f, 0.f, 0.f, 0.f};
    f32x4 a1 = {0.f, 0.f, 0.f, 0.f};
    a0 = __builtin_amdgcn_mfma_f32_16x16x32_bf16(*(const bf16x8*)(wp0), b0, a0, 0, 0, 0);
    a1 = __builtin_amdgcn_mfma_f32_16x16x32_bf16(*(const bf16x8*)(wp1), b0, a1, 0, 0, 0);
    a0 = __builtin_amdgcn_mfma_f32_16x16x32_bf16(*(const bf16x8*)(wp0 + 32), b1, a0, 0, 0, 0);
    a1 = __builtin_amdgcn_mfma_f32_16x16x32_bf16(*(const bf16x8*)(wp1 + 32), b1, a1, 0, 0, 0);
    a0 = __builtin_amdgcn_mfma_f32_16x16x32_bf16(*(const bf16x8*)(wp0 + 64), b2, a0, 0, 0, 0);
    a1 = __builtin_amdgcn_mfma_f32_16x16x32_bf16(*(const bf16x8*)(wp1 + 64), b2, a1, 0, 0, 0);
    a0 = __builtin_amdgcn_mfma_f32_16x16x32_bf16(*(const bf16x8*)(wp0 + 96), b3, a0, 0, 0, 0);
    a1 = __builtin_amdgcn_mfma_f32_16x16x32_bf16(*(const bf16x8*)(wp1 + 96), b3, a1, 0, 0, 0);
    int lc0 = ct0 * 16 + khi * 4;
    int lc1 = ct1 * 16 + khi * 4;
    float4 bb0 = *(const float4*)(bias + cofs + lc0);
    float4 bb1 = *(const float4*)(bias + cofs + lc1);
    if (nok) {
      ushort4 o0, o1;
      o0.x = f2bf(a0[0] + bb0.x); o0.y = f2bf(a0[1] + bb0.y);
      o0.z = f2bf(a0[2] + bb0.z); o0.w = f2bf(a0[3] + bb0.w);
      o1.x = f2bf(a1[0] + bb1.x); o1.y = f2bf(a1[1] + bb1.y);
      o1.z = f2bf(a1[2] + bb1.z); o1.w = f2bf(a1[3] + bb1.w);
      *(ushort4*)(dst + (size_t)node * F1 + cofs + lc0) = o0;
      *(ushort4*)(dst + (size_t)node * F1 + cofs + lc1) = o1;
    }
  }
}

// ---------------- layer-2 GEMM via MFMA: zh bf16 in, halves merged ----------
__global__ __launch_bounds__(256) void k_gemm2_mfma(
    const unsigned short* __restrict__ zh, const unsigned short* __restrict__ Wt2,
    const float* __restrict__ bl, const float* __restrict__ br,
    unsigned short* __restrict__ xl2h, float* __restrict__ xr2, int N) {
  int tid = threadIdx.x, lane = tid & 63, w = tid >> 6;
  int node0 = blockIdx.x * 64 + w * 16;
  int l16 = lane & 15, khi = lane >> 4;
  int koff = khi * 8;
  int arow = node0 + l16; if (arow >= N) arow = N - 1;
  const unsigned short* zp = zh + (size_t)arow * F1 + koff;
  bf16x8 bfr[8];
#pragma unroll
  for (int t = 0; t < 8; t++) bfr[t] = *(const bf16x8*)(zp + 32 * t);
  int node = node0 + l16;
  bool nok = node < N;
#pragma unroll
  for (int half = 0; half < 2; half++) {
    const unsigned short* Wbase = Wt2 + (size_t)half * OUTD * F1;
#pragma unroll
    for (int ct = 0; ct < 4; ct++) {
      int wrow = ct * 16 + l16;
      const unsigned short* wp = Wbase + (size_t)wrow * F1 + koff;
      f32x4 acc = {0.f, 0.f, 0.f, 0.f};
#pragma unroll
      for (int t = 0; t < 8; t++)
        acc = __builtin_amdgcn_mfma_f32_16x16x32_bf16(
            *(const bf16x8*)(wp + 32 * t), bfr[t], acc, 0, 0, 0);
      int cbase = ct * 16 + khi * 4;
      if (half == 0) {
        float4 bb = *(const float4*)(bl + cbase);
        if (nok) {
          ushort4 o;
          o.x = f2bf(acc[0] + bb.x); o.y = f2bf(acc[1] + bb.y);
          o.z = f2bf(acc[2] + bb.z); o.w = f2bf(acc[3] + bb.w);
          *(ushort4*)(xl2h + (size_t)node * OUTD + cbase) = o;
        }
      } else {
        float4 bb = *(const float4*)(br + cbase);
        if (nok) {
          float4 o;
          o.x = acc[0] + bb.x; o.y = acc[1] + bb.y;
          o.z = acc[2] + bb.z; o.w = acc[3] + bb.w;
          *(float4*)(xr2 + (size_t)node * OUTD + cbase) = o;
        }
      }
    }
  }
}

// ---------------- decoder uv GEMM via MFMA: z2h bf16 in ---------------------
__global__ __launch_bounds__(256) void k_uv_mfma(
    const unsigned short* __restrict__ z2h, const unsigned short* __restrict__ Wuv,
    float* __restrict__ u, float* __restrict__ v, int N) {
  int tid = threadIdx.x, lane = tid & 63, w = tid >> 6;
  int node0 = blockIdx.x * 64 + w * 16;
  int half = blockIdx.y;
  int l16 = lane & 15, khi = lane >> 4;
  int koff = khi * 8;
  int arow = node0 + l16; if (arow >= N) arow = N - 1;
  const unsigned short* zp = z2h + (size_t)arow * OUTD + koff;
  bf16x8 b0 = *(const bf16x8*)(zp);
  bf16x8 b1 = *(const bf16x8*)(zp + 32);
  const unsigned short* Wbase = Wuv + (size_t)half * OUTD * OUTD;
  float* dst = half ? v : u;
  int node = node0 + l16;
  bool nok = node < N;
#pragma unroll
  for (int ct = 0; ct < 4; ct++) {
    int wrow = ct * 16 + l16;
    const unsigned short* wp = Wbase + (size_t)wrow * OUTD + koff;
    f32x4 acc = {0.f, 0.f, 0.f, 0.f};
    acc = __builtin_amdgcn_mfma_f32_16x16x32_bf16(*(const bf16x8*)(wp), b0, acc, 0, 0, 0);
    acc = __builtin_amdgcn_mfma_f32_16x16x32_bf16(*(const bf16x8*)(wp + 32), b1, acc, 0, 0, 0);
    int cbase = ct * 16 + khi * 4;
    if (nok) {
      float4 o;
      o.x = acc[0]; o.y = acc[1]; o.z = acc[2]; o.w = acc[3];
      *(float4*)(dst + (size_t)node * OUTD + cbase) = o;
    }
  }
}

// ---------------- CSR scan over 4 privatized copies -------------------------
// scan1: local prefix of per-node TOTALS (copies left intact) -> lps, blk_sum.
__global__ __launch_bounds__(256) void k_scan1(
    const int* __restrict__ cnt4, int N, int* __restrict__ lps,
    int* __restrict__ blk_sum) {
  int t = threadIdx.x, lane = t & 63, wid = t >> 6;
  int base = blockIdx.x * 1024 + t * 4;
  int4 v = {0, 0, 0, 0};
#pragma unroll
  for (int y = 0; y < 4; y++) {
    const int* c = cnt4 + (size_t)y * N;
    if (base + 3 < N) {
      int4 cy = *(const int4*)(c + base);
      v.x += cy.x; v.y += cy.y; v.z += cy.z; v.w += cy.w;
    } else {
      if (base + 0 < N) v.x += c[base + 0];
      if (base + 1 < N) v.y += c[base + 1];
      if (base + 2 < N) v.z += c[base + 2];
      if (base + 3 < N) v.w += c[base + 3];
    }
  }
  int s = v.x + v.y + v.z + v.w;
  int inc = s;
#pragma unroll
  for (int off = 1; off < 64; off <<= 1) {
    int u = __shfl_up(inc, off, 64);
    if (lane >= off) inc += u;
  }
  __shared__ int wsum[4];
  if (lane == 63) wsum[wid] = inc;
  __syncthreads();
  int wofs = 0;
#pragma unroll
  for (int q = 0; q < 4; q++) if (q < wid) wofs += wsum[q];
  int excl = wofs + inc - s;
  int4 o;
  o.x = excl; o.y = excl + v.x; o.z = o.y + v.y; o.w = o.z + v.z;
  if (base + 3 < N) {
    *(int4*)(lps + base) = o;
  } else {
    if (base + 0 < N) lps[base + 0] = o.x;
    if (base + 1 < N) lps[base + 1] = o.y;
    if (base + 2 < N) lps[base + 2] = o.z;
    if (base + 3 < N) lps[base + 3] = o.w;
  }
  if (t == 255) blk_sum[blockIdx.x] = wofs + inc;
}

__global__ void k_scan2(int* __restrict__ blk, int nblk) {
  int lane = threadIdx.x;
  int v = (lane < nblk) ? blk[lane] : 0;
  int inc = v;
#pragma unroll
  for (int off = 1; off < 64; off <<= 1) {
    int u = __shfl_up(inc, off, 64);
    if (lane >= off) inc += u;
  }
  if (lane < nblk) blk[lane] = inc - v;
}

// scan3: row_start[i] = global prefix; cnt4[y*N+i] <- base ptr for copy y.
__global__ __launch_bounds__(256) void k_scan3(
    const int* __restrict__ lps, const int* __restrict__ blk_sum,
    int N, int E, int* __restrict__ row_start, int* __restrict__ cnt4) {
  int i = blockIdx.x * 256 + threadIdx.x;
  if (i < N) {
    int p = lps[i] + blk_sum[i >> 10];
    row_start[i] = p;
    int c0 = cnt4[i];
    int c1 = cnt4[(size_t)N + i];
    int c2 = cnt4[(size_t)2 * N + i];
    cnt4[i] = p;
    cnt4[(size_t)N + i] = p + c0;
    cnt4[(size_t)2 * N + i] = p + c0 + c1;
    cnt4[(size_t)3 * N + i] = p + c0 + c1 + c2;
  }
  if (i == 0) row_start[N] = E;
}

// scatter: pos = cnt4[y*N+d] + rank[e], y = e / per  (atomic-free)
__global__ __launch_bounds__(256) void k_scatter(
    const int* __restrict__ ei, int E, int per, const int* __restrict__ cnt4,
    const int* __restrict__ rank, int* __restrict__ csr_src, int N) {
  int e4 = (blockIdx.x * 256 + threadIdx.x) * 4;
  if (e4 + 3 < E) {
    int4 s = *(const int4*)(ei + e4);
    int4 d = *(const int4*)(ei + E + e4);
    int4 r = *(const int4*)(rank + e4);
    int y0 = e4 / per, y1 = (e4 + 1) / per;
    int y2 = (e4 + 2) / per, y3 = (e4 + 3) / per;
    csr_src[cnt4[(size_t)y0 * N + d.x] + r.x] = s.x;
    csr_src[cnt4[(size_t)y1 * N + d.y] + r.y] = s.y;
    csr_src[cnt4[(size_t)y2 * N + d.z] + r.z] = s.z;
    csr_src[cnt4[(size_t)y3 * N + d.w] + r.w] = s.w;
  } else {
    for (int e = e4; e < E; e++)
      csr_src[cnt4[(size_t)(e / per) * N + ei[E + e]] + rank[e]] = ei[e];
  }
}

// ---------------- DPP 16-lane butterfly sum ---------------------------------
#define DPP_ADD(p, ctrl)                                                     \
  p += __int_as_float(__builtin_amdgcn_update_dpp(                           \
      0, __float_as_int(p), ctrl, 0xF, 0xF, true))
#define RED16(p)  { DPP_ADD(p, 0xB1); DPP_ADD(p, 0x4E);                      \
                    DPP_ADD(p, 0x124); DPP_ADD(p, 0x128); }

#define BF4(dst, h)                                \
  dst.x = bf2f(h.x); dst.y = bf2f(h.y);            \
  dst.z = bf2f(h.z); dst.w = bf2f(h.w);

#define DOTABS(p, xv)                                              \
  { float t;                                                       \
    t = xv.x + xri.x; p = fmaf(t, a6.x, p); p = fmaf(fabsf(t), a4b.x, p); \
    t = xv.y + xri.y; p = fmaf(t, a6.y, p); p = fmaf(fabsf(t), a4b.y, p); \
    t = xv.z + xri.z; p = fmaf(t, a6.z, p); p = fmaf(fabsf(t), a4b.z, p); \
    t = xv.w + xri.w; p = fmaf(t, a6.w, p); p = fmaf(fabsf(t), a4b.w, p); }

#define SETUP_A64(att, stride)                                     \
  float4 a6 = *(const float4*)((att) + (stride));                  \
  a6.x *= LOG2E; a6.y *= LOG2E; a6.z *= LOG2E; a6.w *= LOG2E;      \
  float4 a4b;                                                      \
  a4b.x = 0.4f * a6.x; a4b.y = 0.4f * a6.y;                        \
  a4b.z = 0.4f * a6.z; a4b.w = 0.4f * a6.w;                        \
  a6.x *= 0.6f; a6.y *= 0.6f; a6.z *= 0.6f; a6.w *= 0.6f;

// ---------------- fused layer-1: bf16 xr, bf16 z out ------------------------
__global__ __launch_bounds__(256) void k_fused1(
    const unsigned short* __restrict__ xlh, const unsigned short* __restrict__ xrh,
    const int* __restrict__ row_start, const int* __restrict__ csr_src,
    const float* __restrict__ att, const float* __restrict__ bias,
    unsigned short* __restrict__ zh, int N) {
  int tid = threadIdx.x, lane = tid & 63, w = tid >> 6;
  int i = blockIdx.x * 4 + w;
  if (i >= N) return;
  float4 xri;
  {
    ushort4 hr = *(const ushort4*)(xrh + (size_t)i * F1 + lane * 4);
    BF4(xri, hr);
  }
  SETUP_A64(att, lane * 4);
  float den;
  float4 acc;
  {
    ushort4 hh = *(const ushort4*)(xlh + (size_t)i * F1 + lane * 4);
    float4 xs; BF4(xs, hh);
    float p = 0.f;
    DOTABS(p, xs);
    RED16(p);
    float wt = EXP2F(p);
    den = wt;
    acc.x = wt * xs.x; acc.y = wt * xs.y;
    acc.z = wt * xs.z; acc.w = wt * xs.w;
  }
  int b = row_start[i], e = row_start[i + 1];
  int k = b;
  for (; k + 3 < e; k += 4) {
    int s0 = csr_src[k], s1 = csr_src[k + 1];
    int s2 = csr_src[k + 2], s3 = csr_src[k + 3];
    ushort4 h0 = *(const ushort4*)(xlh + (size_t)s0 * F1 + lane * 4);
    ushort4 h1 = *(const ushort4*)(xlh + (size_t)s1 * F1 + lane * 4);
    ushort4 h2 = *(const ushort4*)(xlh + (size_t)s2 * F1 + lane * 4);
    ushort4 h3 = *(const ushort4*)(xlh + (size_t)s3 * F1 + lane * 4);
    float4 x0, x1, x2, x3;
    BF4(x0, h0); BF4(x1, h1); BF4(x2, h2); BF4(x3, h3);
    float p0 = 0.f, p1 = 0.f, p2 = 0.f, p3 = 0.f;
    DOTABS(p0, x0); DOTABS(p1, x1); DOTABS(p2, x2); DOTABS(p3, x3);
    RED16(p0); RED16(p1); RED16(p2); RED16(p3);
    float w0 = EXP2F(p0), w1 = EXP2F(p1);
    float w2 = EXP2F(p2), w3 = EXP2F(p3);
    den += (w0 + w1) + (w2 + w3);
    acc.x += w0 * x0.x + w1 * x1.x + w2 * x2.x + w3 * x3.x;
    acc.y += w0 * x0.y + w1 * x1.y + w2 * x2.y + w3 * x3.y;
    acc.z += w0 * x0.z + w1 * x1.z + w2 * x2.z + w3 * x3.z;
    acc.w += w0 * x0.w + w1 * x1.w + w2 * x2.w + w3 * x3.w;
  }
  for (; k < e; k++) {
    int s = csr_src[k];
    ushort4 hh = *(const ushort4*)(xlh + (size_t)s * F1 + lane * 4);
    float4 xs;
    BF4(xs, hh);
    float p = 0.f;
    DOTABS(p, xs);
    RED16(p);
    float wt = EXP2F(p);
    den += wt;
    acc.x += wt * xs.x;
    acc.y += wt * xs.y;
    acc.z += wt * xs.z;
    acc.w += wt * xs.w;
  }
  float inv = 1.f / den;
  float4 bz = *(const float4*)(bias + lane * 4);
  ushort4 o;
  o.x = f2bf(fmaxf(acc.x * inv + bz.x, 0.f));
  o.y = f2bf(fmaxf(acc.y * inv + bz.y, 0.f));
  o.z = f2bf(fmaxf(acc.z * inv + bz.z, 0.f));
  o.w = f2bf(fmaxf(acc.w * inv + bz.w, 0.f));
  *(ushort4*)(zh + (size_t)i * F1 + lane * 4) = o;
}

// ---------------- fused layer-2: 4x16 groups, bf16 z2 out -------------------
__global__ __launch_bounds__(256) void k_fused2(
    const unsigned short* __restrict__ xlh, const float* __restrict__ xr,
    const int* __restrict__ row_start, const int* __restrict__ csr_src,
    const float* __restrict__ att, const float* __restrict__ bias,
    unsigned short* __restrict__ z2h, int N) {
  int tid = threadIdx.x, lane = tid & 63, w = tid >> 6;
  int i = blockIdx.x * 4 + w;
  if (i >= N) return;
  int g = lane >> 4, l16 = lane & 15;
  float4 xri = *(const float4*)(xr + (size_t)i * OUTD + l16 * 4);
  SETUP_A64(att, l16 * 4);
  float den = 0.f;
  float4 acc = {0.f, 0.f, 0.f, 0.f};
  if (g == 0) {
    ushort4 hh = *(const ushort4*)(xlh + (size_t)i * OUTD + l16 * 4);
    float4 xs; BF4(xs, hh);
    float p = 0.f;
    DOTABS(p, xs);
    RED16(p);
    float wt = EXP2F(p);
    den = wt;
    acc.x = wt * xs.x; acc.y = wt * xs.y;
    acc.z = wt * xs.z; acc.w = wt * xs.w;
  }
  int b = row_start[i], e = row_start[i + 1];
  int k = b;
  for (; k + 15 < e; k += 16) {
    int ea = k + g, eb = k + 4 + g, ec = k + 8 + g, ed = k + 12 + g;
    int sa = csr_src[ea], sb = csr_src[eb], sc = csr_src[ec], sd = csr_src[ed];
    ushort4 ha = *(const ushort4*)(xlh + (size_t)sa * OUTD + l16 * 4);
    ushort4 hb = *(const ushort4*)(xlh + (size_t)sb * OUTD + l16 * 4);
    ushort4 hc = *(const ushort4*)(xlh + (size_t)sc * OUTD + l16 * 4);
    ushort4 hd = *(const ushort4*)(xlh + (size_t)sd * OUTD + l16 * 4);
    float4 xa, xb, xc, xd;
    BF4(xa, ha); BF4(xb, hb); BF4(xc, hc); BF4(xd, hd);
    float pa = 0.f, pb = 0.f, pc = 0.f, pd = 0.f;
    DOTABS(pa, xa); DOTABS(pb, xb); DOTABS(pc, xc); DOTABS(pd, xd);
    RED16(pa); RED16(pb); RED16(pc); RED16(pd);
    float wa = EXP2F(pa), wb = EXP2F(pb), wc = EXP2F(pc), wd = EXP2F(pd);
    den += (wa + wb) + (wc + wd);
    acc.x += (wa * xa.x + wb * xb.x) + (wc * xc.x + wd * xd.x);
    acc.y += (wa * xa.y + wb * xb.y) + (wc * xc.y + wd * xd.y);
    acc.z += (wa * xa.z + wb * xb.z) + (wc * xc.z + wd * xd.z);
    acc.w += (wa * xa.w + wb * xb.w) + (wc * xc.w + wd * xd.w);
  }
  for (; k < e; k += 8) {
    int ea = k + g, eb = k + 4 + g;
    int sa = csr_src[ea < e ? ea : (e - 1)];
    int sb = csr_src[eb < e ? eb : (e - 1)];
    ushort4 ha = *(const ushort4*)(xlh + (size_t)sa * OUTD + l16 * 4);
    ushort4 hb = *(const ushort4*)(xlh + (size_t)sb * OUTD + l16 * 4);
    float4 xa, xb;
    BF4(xa, ha); BF4(xb, hb);
    float pa = 0.f, pb = 0.f;
    DOTABS(pa, xa); DOTABS(pb, xb);
    RED16(pa); RED16(pb);
    float wa = (ea < e) ? EXP2F(pa) : 0.f;
    float wb = (eb < e) ? EXP2F(pb) : 0.f;
    den += wa + wb;
    acc.x += wa * xa.x + wb * xb.x;
    acc.y += wa * xa.y + wb * xb.y;
    acc.z += wa * xa.z + wb * xb.z;
    acc.w += wa * xa.w + wb * xb.w;
  }
#pragma unroll
  for (int off = 16; off <= 32; off <<= 1) {
    den   += __shfl_xor(den, off, 64);
    acc.x += __shfl_xor(acc.x, off, 64);
    acc.y += __shfl_xor(acc.y, off, 64);
    acc.z += __shfl_xor(acc.z, off, 64);
    acc.w += __shfl_xor(acc.w, off, 64);
  }
  if (g == 0) {
    float inv = 1.f / den;
    float4 bz = *(const float4*)(bias + l16 * 4);
    ushort4 o;
    o.x = f2bf(acc.x * inv + bz.x);
    o.y = f2bf(acc.y * inv + bz.y);
    o.z = f2bf(acc.z * inv + bz.z);
    o.w = f2bf(acc.w * inv + bz.w);
    *(ushort4*)(z2h + (size_t)i * OUTD + l16 * 4) = o;
  }
}

// ---------------- decoder stage B ------------------------------------------
__global__ __launch_bounds__(256) void k_link(
    const float* __restrict__ u, const float* __restrict__ v,
    const int* __restrict__ eli, int EL,
    const float* __restrict__ bm1, const float* __restrict__ Wm2,
    const float* __restrict__ bm2, float* __restrict__ out) {
  int tid = threadIdx.x, lane = tid & 63, w = tid >> 6;
  int li = lane >> 4, c4 = (lane & 15) * 4;
  int l = (blockIdx.x * 4 + w) * 4 + li;
  if (l >= EL) return;
  int a = eli[l], b = eli[EL + l];
  float4 uu = *(const float4*)(u + (size_t)a * OUTD + c4);
  float4 vv = *(const float4*)(v + (size_t)b * OUTD + c4);
  float4 bb = *(const float4*)(bm1 + c4);
  float4 ww = *(const float4*)(Wm2 + c4);
  float p = fmaxf(uu.x + vv.x + bb.x, 0.f) * ww.x
          + fmaxf(uu.y + vv.y + bb.y, 0.f) * ww.y
          + fmaxf(uu.z + vv.z + bb.z, 0.f) * ww.z
          + fmaxf(uu.w + vv.w + bb.w, 0.f) * ww.w;
  RED16(p);
  if ((lane & 15) == 0) out[l] = p + bm2[0];
}

extern "C" void kernel_launch(void* const* d_in, const int* in_sizes, int n_in,
                              void* d_out, int out_size, void* d_ws, size_t ws_size,
                              hipStream_t stream) {
  const float* x     = (const float*)d_in[0];
  const int*   ei    = (const int*)d_in[1];
  const int*   eli   = (const int*)d_in[2];
  const float* W1l   = (const float*)d_in[3];
  const float* b1l   = (const float*)d_in[4];
  const float* W1r   = (const float*)d_in[5];
  const float* b1r   = (const float*)d_in[6];
  const float* att1  = (const float*)d_in[7];
  const float* bias1 = (const float*)d_in[8];
  const float* W2l   = (const float*)d_in[9];
  const float* b2l   = (const float*)d_in[10];
  const float* W2r   = (const float*)d_in[11];
  const float* b2r   = (const float*)d_in[12];
  const float* att2  = (const float*)d_in[13];
  const float* bias2 = (const float*)d_in[14];
  const float* Wm1   = (const float*)d_in[15];
  const float* bm1   = (const float*)d_in[16];
  const float* Wm2   = (const float*)d_in[17];
  const float* bm2   = (const float*)d_in[18];

  int N = in_sizes[0] / IN_DIM;   // 50000
  int E = in_sizes[1] / 2;        // 800000
  int EL = in_sizes[2] / 2;       // 200000

  // ---- workspace layout (bytes) ----
  // [0, 25.6M)      xlh bf16        (layer2: xl2h bf16 @0, xr2 f32 @12.8M)
  // [25.6M, 38.4M)  xb bf16         (layer2: z2h bf16 @25.6M after gemm1 dead)
  // [38.4M..39.3M)  Wt, Wt2, Wuv
  // [51.2M, 76.8M)  xrh bf16        (decoder: u @51.2M, v @64M)
  // [76.8M, 102.4M) zh bf16
  // [102.4M..]      row_start | csr_src @103.0M | blk_sum @106.3M
  //                 rank @106.4M | cnt4(4N) @109.7M | lps @110.6M
  char* ws = (char*)d_ws;
  unsigned short* xlh  = (unsigned short*)(ws);
  unsigned short* xb   = (unsigned short*)(ws + 25600000);
  unsigned short* Wt   = (unsigned short*)(ws + 38400000);
  unsigned short* Wt2  = (unsigned short*)(ws + 39000000);
  unsigned short* Wuv  = (unsigned short*)(ws + 39200000);
  unsigned short* xrh  = (unsigned short*)(ws + 51200000);
  unsigned short* zh   = (unsigned short*)(ws + 76800000);
  int*   row_start = (int*)(ws + 102400000);
  int*   csr_src   = (int*)(ws + 103000000);
  int*   blk_sum   = (int*)(ws + 106300000);
  int*   rank      = (int*)(ws + 106400000);
  int*   cnt4      = (int*)(ws + 109700000);
  int*   lps       = (int*)(ws + 110600000);
  unsigned short* xl2h = (unsigned short*)(ws);
  float* xr2       = (float*)(ws + 12800000);
  unsigned short* z2h  = (unsigned short*)(ws + 25600000);
  float* u_buf     = (float*)(ws + 51200000);
  float* v_buf     = (float*)(ws + 64000000);

  int nblk = (N + 1023) / 1024;   // 49 (<=64 required by k_scan2)
  int NX8 = N * IN_DIM / 8;       // 800000
  int gx = (N + 63) / 64;         // 782
  int per = gx * 256;             // 200192 edges per y-copy
  int cvt_total = NX8 + 4 * N;    // covers cnt4 zero + all weights (4N > 106496)

  // ---- conversions (+cnt4 zero); gemm1 fuses y-privatized rank-hist ----
  k_cvt_all<<<(cvt_total + 255) / 256, 256, 0, stream>>>(
      x, xb, NX8, W1l, W1r, W2l, W2r, Wm1, Wt, Wt2, Wuv, cnt4, N);
  {
    dim3 g1(gx, 4);
    k_gemm1_mfma<<<g1, 256, 0, stream>>>(xb, Wt, b1l, b1r, xlh, xrh,
                                         ei, E, cnt4, rank, N);
  }
  k_scan1<<<nblk, 256, 0, stream>>>(cnt4, N, lps, blk_sum);
  k_scan2<<<1, 64, 0, stream>>>(blk_sum, nblk);
  k_scan3<<<(N + 255) / 256, 256, 0, stream>>>(lps, blk_sum, N, E,
                                               row_start, cnt4);
  k_scatter<<<(E / 4 + 255) / 256, 256, 0, stream>>>(ei, E, per, cnt4, rank,
                                                     csr_src, N);

  // ---- layer 1 (fused) ----
  k_fused1<<<(N + 3) / 4, 256, 0, stream>>>(xlh, xrh, row_start, csr_src,
                                            att1, bias1, zh, N);
  // ---- layer 2 ----
  k_gemm2_mfma<<<(N + 63) / 64, 256, 0, stream>>>(zh, Wt2, b2l, b2r, xl2h, xr2, N);
  k_fused2<<<(N + 3) / 4, 256, 0, stream>>>(xl2h, xr2, row_start, csr_src,
                                            att2, bias2, z2h, N);
  // ---- decoder ----
  {
    dim3 g3((N + 63) / 64, 2);
    k_uv_mfma<<<g3, 256, 0, stream>>>(z2h, Wuv, u_buf, v_buf, N);
  }
  k_link<<<(EL + 15) / 16, 256, 0, stream>>>(u_buf, v_buf, eli, EL,
                                             bm1, Wm2, bm2, (float*)d_out);
}

// Round 29
// 259.167 us; speedup vs baseline: 1.0076x; 1.0076x over previous
//
#include <hip/hip_runtime.h>
#include <hip/hip_bf16.h>

#define IN_DIM 128
#define HID    64
#define NH     4
#define F1     256   // NH*HID
#define OUTD   64
#define NEG    0.2f
#define LOG2E  1.44269504088896f

#define EXP2F(x) __builtin_amdgcn_exp2f(x)

typedef __attribute__((ext_vector_type(8))) short bf16x8;
typedef __attribute__((ext_vector_type(4))) float f32x4;
typedef __attribute__((ext_vector_type(4))) unsigned short u16x4;

__device__ __forceinline__ float bf2f(unsigned short h) {
  return __uint_as_float((unsigned)h << 16);
}
__device__ __forceinline__ unsigned short f2bf(float f) {
  unsigned u = __float_as_uint(f);
  u += 0x7fffu + ((u >> 16) & 1u);   // RTNE
  return (unsigned short)(u >> 16);
}
__device__ __forceinline__ bf16x8 f2bf8(const float* p) {
  float4 lo = *(const float4*)p;
  float4 hi = *(const float4*)(p + 4);
  bf16x8 r;
  r[0] = (short)f2bf(lo.x); r[1] = (short)f2bf(lo.y);
  r[2] = (short)f2bf(lo.z); r[3] = (short)f2bf(lo.w);
  r[4] = (short)f2bf(hi.x); r[5] = (short)f2bf(hi.y);
  r[6] = (short)f2bf(hi.z); r[7] = (short)f2bf(hi.w);
  return r;
}

// ---------------- fused conversions: x->bf16, weights, cnt4 zero ------------
__global__ __launch_bounds__(256) void k_cvt_all(
    const float* __restrict__ x, unsigned short* __restrict__ xb, int NX8,
    const float* __restrict__ W1l, const float* __restrict__ W1r,
    const float* __restrict__ W2l, const float* __restrict__ W2r,
    const float* __restrict__ Wm1,
    unsigned short* __restrict__ Wt, unsigned short* __restrict__ Wt2,
    unsigned short* __restrict__ Wuv, int* __restrict__ cnt4, int N) {
  int idx = blockIdx.x * 256 + threadIdx.x;
  if (idx < NX8) {
    bf16x8 r = f2bf8(x + (size_t)idx * 8);
    *(bf16x8*)(xb + (size_t)idx * 8) = r;
    return;
  }
  int j0 = idx - NX8;
  if (j0 < 4 * N) cnt4[j0] = 0;
  if (j0 < 512 * IN_DIM) {
    int c = j0 >> 7, k = j0 & 127;
    float v = (c < F1) ? W1l[k * F1 + c] : W1r[k * F1 + (c - F1)];
    Wt[j0] = f2bf(v);
  } else if (j0 < 512 * IN_DIM + 128 * F1) {
    int j = j0 - 512 * IN_DIM;
    int c = j >> 8, k = j & 255;
    float v = (c < OUTD) ? W2l[k * OUTD + c] : W2r[k * OUTD + (c - OUTD)];
    Wt2[j] = f2bf(v);
  } else if (j0 < 512 * IN_DIM + 128 * F1 + 128 * OUTD) {
    int j = j0 - 512 * IN_DIM - 128 * F1;
    int c = j >> 6, k = j & 63;
    float v = (c < OUTD) ? Wm1[k * OUTD + c] : Wm1[(64 + k) * OUTD + (c - OUTD)];
    Wuv[j] = f2bf(v);
  }
}

// ---------------- layer-1 GEMM via MFMA + y-privatized rank-hist ------------
// grid ((N+63)/64, 4). NON-TEMPORAL output stores protect xb/Wt L2 residency.
__global__ __launch_bounds__(256) void k_gemm1_mfma(
    const unsigned short* __restrict__ xb, const unsigned short* __restrict__ Wt,
    const float* __restrict__ bl, const float* __restrict__ br,
    unsigned short* __restrict__ xlh, unsigned short* __restrict__ xrh,
    const int* __restrict__ ei, int E, int* __restrict__ cnt4,
    int* __restrict__ rank, int N) {
  int tid = threadIdx.x, lane = tid & 63, w = tid >> 6;
  int node0 = blockIdx.x * 64 + w * 16;
  int colbase = blockIdx.y * 128;
  int l16 = lane & 15, khi = lane >> 4;
  int koff = khi * 8;
  int arow = node0 + l16; if (arow >= N) arow = N - 1;
  const unsigned short* ap = xb + (size_t)arow * IN_DIM + koff;
  bf16x8 b0 = *(const bf16x8*)(ap);
  bf16x8 b1 = *(const bf16x8*)(ap + 32);
  bf16x8 b2 = *(const bf16x8*)(ap + 64);
  bf16x8 b3 = *(const bf16x8*)(ap + 96);
  // fused histogram: 1 edge/thread into the y-private copy
  {
    int gid = blockIdx.y * gridDim.x + blockIdx.x;
    int e = gid * 256 + tid;
    if (e < E) {
      int d = ei[E + e];
      rank[e] = atomicAdd(&cnt4[blockIdx.y * N + d], 1);
    }
  }
  int node = node0 + l16;
  bool nok = node < N;
  bool isL = (colbase < F1);
  unsigned short* dst = isL ? xlh : xrh;
  const float* bias = isL ? bl : br;
  int cofs = isL ? colbase : (colbase - F1);
#pragma unroll
  for (int cp = 0; cp < 4; cp++) {
    int ct0 = cp * 2, ct1 = cp * 2 + 1;
    const unsigned short* wp0 = Wt + (size_t)(colbase + ct0 * 16 + l16) * IN_DIM + koff;
    const unsigned short* wp1 = Wt + (size_t)(colbase + ct1 * 16 + l16) * IN_DIM + koff;
    f32x4 a0 = {0.f, 0.f, 0.f, 0.f};
    f32x4 a1 = {0.f, 0.f, 0.f, 0.f};
    a0 = __builtin_amdgcn_mfma_f32_16x16x32_bf16(*(const bf16x8*)(wp0), b0, a0, 0, 0, 0);
    a1 = __builtin_amdgcn_mfma_f32_16x16x32_bf16(*(const bf16x8*)(wp1), b0, a1, 0, 0, 0);
    a0 = __builtin_amdgcn_mfma_f32_16x16x32_bf16(*(const bf16x8*)(wp0 + 32), b1, a0, 0, 0, 0);
    a1 = __builtin_amdgcn_mfma_f32_16x16x32_bf16(*(const bf16x8*)(wp1 + 32), b1, a1, 0, 0, 0);
    a0 = __builtin_amdgcn_mfma_f32_16x16x32_bf16(*(const bf16x8*)(wp0 + 64), b2, a0, 0, 0, 0);
    a1 = __builtin_amdgcn_mfma_f32_16x16x32_bf16(*(const bf16x8*)(wp1 + 64), b2, a1, 0, 0, 0);
    a0 = __builtin_amdgcn_mfma_f32_16x16x32_bf16(*(const bf16x8*)(wp0 + 96), b3, a0, 0, 0, 0);
    a1 = __builtin_amdgcn_mfma_f32_16x16x32_bf16(*(const bf16x8*)(wp1 + 96), b3, a1, 0, 0, 0);
    int lc0 = ct0 * 16 + khi * 4;
    int lc1 = ct1 * 16 + khi * 4;
    float4 bb0 = *(const float4*)(bias + cofs + lc0);
    float4 bb1 = *(const float4*)(bias + cofs + lc1);
    if (nok) {
      u16x4 o0, o1;
      o0[0] = f2bf(a0[0] + bb0.x); o0[1] = f2bf(a0[1] + bb0.y);
      o0[2] = f2bf(a0[2] + bb0.z); o0[3] = f2bf(a0[3] + bb0.w);
      o1[0] = f2bf(a1[0] + bb1.x); o1[1] = f2bf(a1[1] + bb1.y);
      o1[2] = f2bf(a1[2] + bb1.z); o1[3] = f2bf(a1[3] + bb1.w);
      __builtin_nontemporal_store(o0, (u16x4*)(dst + (size_t)node * F1 + cofs + lc0));
      __builtin_nontemporal_store(o1, (u16x4*)(dst + (size_t)node * F1 + cofs + lc1));
    }
  }
}

// ---------------- layer-2 GEMM via MFMA: zh bf16 in, both outs bf16 ---------
__global__ __launch_bounds__(256) void k_gemm2_mfma(
    const unsigned short* __restrict__ zh, const unsigned short* __restrict__ Wt2,
    const float* __restrict__ bl, const float* __restrict__ br,
    unsigned short* __restrict__ xl2h, unsigned short* __restrict__ xr2h, int N) {
  int tid = threadIdx.x, lane = tid & 63, w = tid >> 6;
  int node0 = blockIdx.x * 64 + w * 16;
  int l16 = lane & 15, khi = lane >> 4;
  int koff = khi * 8;
  int arow = node0 + l16; if (arow >= N) arow = N - 1;
  const unsigned short* zp = zh + (size_t)arow * F1 + koff;
  bf16x8 bfr[8];
#pragma unroll
  for (int t = 0; t < 8; t++) bfr[t] = *(const bf16x8*)(zp + 32 * t);
  int node = node0 + l16;
  bool nok = node < N;
#pragma unroll
  for (int half = 0; half < 2; half++) {
    const unsigned short* Wbase = Wt2 + (size_t)half * OUTD * F1;
    unsigned short* dst = half ? xr2h : xl2h;
    const float* bias = half ? br : bl;
#pragma unroll
    for (int ct = 0; ct < 4; ct++) {
      int wrow = ct * 16 + l16;
      const unsigned short* wp = Wbase + (size_t)wrow * F1 + koff;
      f32x4 acc = {0.f, 0.f, 0.f, 0.f};
#pragma unroll
      for (int t = 0; t < 8; t++)
        acc = __builtin_amdgcn_mfma_f32_16x16x32_bf16(
            *(const bf16x8*)(wp + 32 * t), bfr[t], acc, 0, 0, 0);
      int cbase = ct * 16 + khi * 4;
      float4 bb = *(const float4*)(bias + cbase);
      if (nok) {
        ushort4 o;
        o.x = f2bf(acc[0] + bb.x); o.y = f2bf(acc[1] + bb.y);
        o.z = f2bf(acc[2] + bb.z); o.w = f2bf(acc[3] + bb.w);
        *(ushort4*)(dst + (size_t)node * OUTD + cbase) = o;
      }
    }
  }
}

// ---------------- decoder uv GEMM via MFMA: z2h bf16 in ---------------------
__global__ __launch_bounds__(256) void k_uv_mfma(
    const unsigned short* __restrict__ z2h, const unsigned short* __restrict__ Wuv,
    float* __restrict__ u, float* __restrict__ v, int N) {
  int tid = threadIdx.x, lane = tid & 63, w = tid >> 6;
  int node0 = blockIdx.x * 64 + w * 16;
  int half = blockIdx.y;
  int l16 = lane & 15, khi = lane >> 4;
  int koff = khi * 8;
  int arow = node0 + l16; if (arow >= N) arow = N - 1;
  const unsigned short* zp = z2h + (size_t)arow * OUTD + koff;
  bf16x8 b0 = *(const bf16x8*)(zp);
  bf16x8 b1 = *(const bf16x8*)(zp + 32);
  const unsigned short* Wbase = Wuv + (size_t)half * OUTD * OUTD;
  float* dst = half ? v : u;
  int node = node0 + l16;
  bool nok = node < N;
#pragma unroll
  for (int ct = 0; ct < 4; ct++) {
    int wrow = ct * 16 + l16;
    const unsigned short* wp = Wbase + (size_t)wrow * OUTD + koff;
    f32x4 acc = {0.f, 0.f, 0.f, 0.f};
    acc = __builtin_amdgcn_mfma_f32_16x16x32_bf16(*(const bf16x8*)(wp), b0, acc, 0, 0, 0);
    acc = __builtin_amdgcn_mfma_f32_16x16x32_bf16(*(const bf16x8*)(wp + 32), b1, acc, 0, 0, 0);
    int cbase = ct * 16 + khi * 4;
    if (nok) {
      float4 o;
      o.x = acc[0]; o.y = acc[1]; o.z = acc[2]; o.w = acc[3];
      *(float4*)(dst + (size_t)node * OUTD + cbase) = o;
    }
  }
}

// ---------------- CSR scan over 4 privatized copies -------------------------
__global__ __launch_bounds__(256) void k_scan1(
    const int* __restrict__ cnt4, int N, int* __restrict__ lps,
    int* __restrict__ blk_sum) {
  int t = threadIdx.x, lane = t & 63, wid = t >> 6;
  int base = blockIdx.x * 1024 + t * 4;
  int4 v = {0, 0, 0, 0};
#pragma unroll
  for (int y = 0; y < 4; y++) {
    const int* c = cnt4 + (size_t)y * N;
    if (base + 3 < N) {
      int4 cy = *(const int4*)(c + base);
      v.x += cy.x; v.y += cy.y; v.z += cy.z; v.w += cy.w;
    } else {
      if (base + 0 < N) v.x += c[base + 0];
      if (base + 1 < N) v.y += c[base + 1];
      if (base + 2 < N) v.z += c[base + 2];
      if (base + 3 < N) v.w += c[base + 3];
    }
  }
  int s = v.x + v.y + v.z + v.w;
  int inc = s;
#pragma unroll
  for (int off = 1; off < 64; off <<= 1) {
    int u = __shfl_up(inc, off, 64);
    if (lane >= off) inc += u;
  }
  __shared__ int wsum[4];
  if (lane == 63) wsum[wid] = inc;
  __syncthreads();
  int wofs = 0;
#pragma unroll
  for (int q = 0; q < 4; q++) if (q < wid) wofs += wsum[q];
  int excl = wofs + inc - s;
  int4 o;
  o.x = excl; o.y = excl + v.x; o.z = o.y + v.y; o.w = o.z + v.z;
  if (base + 3 < N) {
    *(int4*)(lps + base) = o;
  } else {
    if (base + 0 < N) lps[base + 0] = o.x;
    if (base + 1 < N) lps[base + 1] = o.y;
    if (base + 2 < N) lps[base + 2] = o.z;
    if (base + 3 < N) lps[base + 3] = o.w;
  }
  if (t == 255) blk_sum[blockIdx.x] = wofs + inc;
}

__global__ void k_scan2(int* __restrict__ blk, int nblk) {
  int lane = threadIdx.x;
  int v = (lane < nblk) ? blk[lane] : 0;
  int inc = v;
#pragma unroll
  for (int off = 1; off < 64; off <<= 1) {
    int u = __shfl_up(inc, off, 64);
    if (lane >= off) inc += u;
  }
  if (lane < nblk) blk[lane] = inc - v;
}

__global__ __launch_bounds__(256) void k_scan3(
    const int* __restrict__ lps, const int* __restrict__ blk_sum,
    int N, int E, int* __restrict__ row_start, int* __restrict__ cnt4) {
  int i = blockIdx.x * 256 + threadIdx.x;
  if (i < N) {
    int p = lps[i] + blk_sum[i >> 10];
    row_start[i] = p;
    int c0 = cnt4[i];
    int c1 = cnt4[(size_t)N + i];
    int c2 = cnt4[(size_t)2 * N + i];
    cnt4[i] = p;
    cnt4[(size_t)N + i] = p + c0;
    cnt4[(size_t)2 * N + i] = p + c0 + c1;
    cnt4[(size_t)3 * N + i] = p + c0 + c1 + c2;
  }
  if (i == 0) row_start[N] = E;
}

__global__ __launch_bounds__(256) void k_scatter(
    const int* __restrict__ ei, int E, int per, const int* __restrict__ cnt4,
    const int* __restrict__ rank, int* __restrict__ csr_src, int N) {
  int e4 = (blockIdx.x * 256 + threadIdx.x) * 4;
  if (e4 + 3 < E) {
    int4 s = *(const int4*)(ei + e4);
    int4 d = *(const int4*)(ei + E + e4);
    int4 r = *(const int4*)(rank + e4);
    int y0 = e4 / per, y1 = (e4 + 1) / per;
    int y2 = (e4 + 2) / per, y3 = (e4 + 3) / per;
    csr_src[cnt4[(size_t)y0 * N + d.x] + r.x] = s.x;
    csr_src[cnt4[(size_t)y1 * N + d.y] + r.y] = s.y;
    csr_src[cnt4[(size_t)y2 * N + d.z] + r.z] = s.z;
    csr_src[cnt4[(size_t)y3 * N + d.w] + r.w] = s.w;
  } else {
    for (int e = e4; e < E; e++)
      csr_src[cnt4[(size_t)(e / per) * N + ei[E + e]] + rank[e]] = ei[e];
  }
}

// ---------------- DPP 16-lane butterfly sum ---------------------------------
#define DPP_ADD(p, ctrl)                                                     \
  p += __int_as_float(__builtin_amdgcn_update_dpp(                           \
      0, __float_as_int(p), ctrl, 0xF, 0xF, true))
#define RED16(p)  { DPP_ADD(p, 0xB1); DPP_ADD(p, 0x4E);                      \
                    DPP_ADD(p, 0x124); DPP_ADD(p, 0x128); }

#define BF4(dst, h)                                \
  dst.x = bf2f(h.x); dst.y = bf2f(h.y);            \
  dst.z = bf2f(h.z); dst.w = bf2f(h.w);

#define DOTABS(p, xv)                                              \
  { float t;                                                       \
    t = xv.x + xri.x; p = fmaf(t, a6.x, p); p = fmaf(fabsf(t), a4b.x, p); \
    t = xv.y + xri.y; p = fmaf(t, a6.y, p); p = fmaf(fabsf(t), a4b.y, p); \
    t = xv.z + xri.z; p = fmaf(t, a6.z, p); p = fmaf(fabsf(t), a4b.z, p); \
    t = xv.w + xri.w; p = fmaf(t, a6.w, p); p = fmaf(fabsf(t), a4b.w, p); }

#define SETUP_A64(att, stride)                                     \
  float4 a6 = *(const float4*)((att) + (stride));                  \
  a6.x *= LOG2E; a6.y *= LOG2E; a6.z *= LOG2E; a6.w *= LOG2E;      \
  float4 a4b;                                                      \
  a4b.x = 0.4f * a6.x; a4b.y = 0.4f * a6.y;                        \
  a4b.z = 0.4f * a6.z; a4b.w = 0.4f * a6.w;                        \
  a6.x *= 0.6f; a6.y *= 0.6f; a6.z *= 0.6f; a6.w *= 0.6f;

// ---------------- fused layer-1: bf16 in/out --------------------------------
__global__ __launch_bounds__(256) void k_fused1(
    const unsigned short* __restrict__ xlh, const unsigned short* __restrict__ xrh,
    const int* __restrict__ row_start, const int* __restrict__ csr_src,
    const float* __restrict__ att, const float* __restrict__ bias,
    unsigned short* __restrict__ zh, int N) {
  int tid = threadIdx.x, lane = tid & 63, w = tid >> 6;
  int i = blockIdx.x * 4 + w;
  if (i >= N) return;
  float4 xri;
  {
    ushort4 hr = *(const ushort4*)(xrh + (size_t)i * F1 + lane * 4);
    BF4(xri, hr);
  }
  SETUP_A64(att, lane * 4);
  float den;
  float4 acc;
  {
    ushort4 hh = *(const ushort4*)(xlh + (size_t)i * F1 + lane * 4);
    float4 xs; BF4(xs, hh);
    float p = 0.f;
    DOTABS(p, xs);
    RED16(p);
    float wt = EXP2F(p);
    den = wt;
    acc.x = wt * xs.x; acc.y = wt * xs.y;
    acc.z = wt * xs.z; acc.w = wt * xs.w;
  }
  int b = row_start[i], e = row_start[i + 1];
  int k = b;
  for (; k + 3 < e; k += 4) {
    int s0 = csr_src[k], s1 = csr_src[k + 1];
    int s2 = csr_src[k + 2], s3 = csr_src[k + 3];
    ushort4 h0 = *(const ushort4*)(xlh + (size_t)s0 * F1 + lane * 4);
    ushort4 h1 = *(const ushort4*)(xlh + (size_t)s1 * F1 + lane * 4);
    ushort4 h2 = *(const ushort4*)(xlh + (size_t)s2 * F1 + lane * 4);
    ushort4 h3 = *(const ushort4*)(xlh + (size_t)s3 * F1 + lane * 4);
    float4 x0, x1, x2, x3;
    BF4(x0, h0); BF4(x1, h1); BF4(x2, h2); BF4(x3, h3);
    float p0 = 0.f, p1 = 0.f, p2 = 0.f, p3 = 0.f;
    DOTABS(p0, x0); DOTABS(p1, x1); DOTABS(p2, x2); DOTABS(p3, x3);
    RED16(p0); RED16(p1); RED16(p2); RED16(p3);
    float w0 = EXP2F(p0), w1 = EXP2F(p1);
    float w2 = EXP2F(p2), w3 = EXP2F(p3);
    den += (w0 + w1) + (w2 + w3);
    acc.x += w0 * x0.x + w1 * x1.x + w2 * x2.x + w3 * x3.x;
    acc.y += w0 * x0.y + w1 * x1.y + w2 * x2.y + w3 * x3.y;
    acc.z += w0 * x0.z + w1 * x1.z + w2 * x2.z + w3 * x3.z;
    acc.w += w0 * x0.w + w1 * x1.w + w2 * x2.w + w3 * x3.w;
  }
  for (; k < e; k++) {
    int s = csr_src[k];
    ushort4 hh = *(const ushort4*)(xlh + (size_t)s * F1 + lane * 4);
    float4 xs;
    BF4(xs, hh);
    float p = 0.f;
    DOTABS(p, xs);
    RED16(p);
    float wt = EXP2F(p);
    den += wt;
    acc.x += wt * xs.x;
    acc.y += wt * xs.y;
    acc.z += wt * xs.z;
    acc.w += wt * xs.w;
  }
  float inv = 1.f / den;
  float4 bz = *(const float4*)(bias + lane * 4);
  ushort4 o;
  o.x = f2bf(fmaxf(acc.x * inv + bz.x, 0.f));
  o.y = f2bf(fmaxf(acc.y * inv + bz.y, 0.f));
  o.z = f2bf(fmaxf(acc.z * inv + bz.z, 0.f));
  o.w = f2bf(fmaxf(acc.w * inv + bz.w, 0.f));
  *(ushort4*)(zh + (size_t)i * F1 + lane * 4) = o;
}

// ---------------- fused layer-2: 4x16 groups, bf16 in/out -------------------
__global__ __launch_bounds__(256) void k_fused2(
    const unsigned short* __restrict__ xlh, const unsigned short* __restrict__ xrh2,
    const int* __restrict__ row_start, const int* __restrict__ csr_src,
    const float* __restrict__ att, const float* __restrict__ bias,
    unsigned short* __restrict__ z2h, int N) {
  int tid = threadIdx.x, lane = tid & 63, w = tid >> 6;
  int i = blockIdx.x * 4 + w;
  if (i >= N) return;
  int g = lane >> 4, l16 = lane & 15;
  float4 xri;
  {
    ushort4 hr = *(const ushort4*)(xrh2 + (size_t)i * OUTD + l16 * 4);
    BF4(xri, hr);
  }
  SETUP_A64(att, l16 * 4);
  float den = 0.f;
  float4 acc = {0.f, 0.f, 0.f, 0.f};
  if (g == 0) {
    ushort4 hh = *(const ushort4*)(xlh + (size_t)i * OUTD + l16 * 4);
    float4 xs; BF4(xs, hh);
    float p = 0.f;
    DOTABS(p, xs);
    RED16(p);
    float wt = EXP2F(p);
    den = wt;
    acc.x = wt * xs.x; acc.y = wt * xs.y;
    acc.z = wt * xs.z; acc.w = wt * xs.w;
  }
  int b = row_start[i], e = row_start[i + 1];
  int k = b;
  for (; k + 15 < e; k += 16) {
    int ea = k + g, eb = k + 4 + g, ec = k + 8 + g, ed = k + 12 + g;
    int sa = csr_src[ea], sb = csr_src[eb], sc = csr_src[ec], sd = csr_src[ed];
    ushort4 ha = *(const ushort4*)(xlh + (size_t)sa * OUTD + l16 * 4);
    ushort4 hb = *(const ushort4*)(xlh + (size_t)sb * OUTD + l16 * 4);
    ushort4 hc = *(const ushort4*)(xlh + (size_t)sc * OUTD + l16 * 4);
    ushort4 hd = *(const ushort4*)(xlh + (size_t)sd * OUTD + l16 * 4);
    float4 xa, xb, xc, xd;
    BF4(xa, ha); BF4(xb, hb); BF4(xc, hc); BF4(xd, hd);
    float pa = 0.f, pb = 0.f, pc = 0.f, pd = 0.f;
    DOTABS(pa, xa); DOTABS(pb, xb); DOTABS(pc, xc); DOTABS(pd, xd);
    RED16(pa); RED16(pb); RED16(pc); RED16(pd);
    float wa = EXP2F(pa), wb = EXP2F(pb), wc = EXP2F(pc), wd = EXP2F(pd);
    den += (wa + wb) + (wc + wd);
    acc.x += (wa * xa.x + wb * xb.x) + (wc * xc.x + wd * xd.x);
    acc.y += (wa * xa.y + wb * xb.y) + (wc * xc.y + wd * xd.y);
    acc.z += (wa * xa.z + wb * xb.z) + (wc * xc.z + wd * xd.z);
    acc.w += (wa * xa.w + wb * xb.w) + (wc * xc.w + wd * xd.w);
  }
  for (; k < e; k += 8) {
    int ea = k + g, eb = k + 4 + g;
    int sa = csr_src[ea < e ? ea : (e - 1)];
    int sb = csr_src[eb < e ? eb : (e - 1)];
    ushort4 ha = *(const ushort4*)(xlh + (size_t)sa * OUTD + l16 * 4);
    ushort4 hb = *(const ushort4*)(xlh + (size_t)sb * OUTD + l16 * 4);
    float4 xa, xb;
    BF4(xa, ha); BF4(xb, hb);
    float pa = 0.f, pb = 0.f;
    DOTABS(pa, xa); DOTABS(pb, xb);
    RED16(pa); RED16(pb);
    float wa = (ea < e) ? EXP2F(pa) : 0.f;
    float wb = (eb < e) ? EXP2F(pb) : 0.f;
    den += wa + wb;
    acc.x += wa * xa.x + wb * xb.x;
    acc.y += wa * xa.y + wb * xb.y;
    acc.z += wa * xa.z + wb * xb.z;
    acc.w += wa * xa.w + wb * xb.w;
  }
#pragma unroll
  for (int off = 16; off <= 32; off <<= 1) {
    den   += __shfl_xor(den, off, 64);
    acc.x += __shfl_xor(acc.x, off, 64);
    acc.y += __shfl_xor(acc.y, off, 64);
    acc.z += __shfl_xor(acc.z, off, 64);
    acc.w += __shfl_xor(acc.w, off, 64);
  }
  if (g == 0) {
    float inv = 1.f / den;
    float4 bz = *(const float4*)(bias + l16 * 4);
    ushort4 o;
    o.x = f2bf(acc.x * inv + bz.x);
    o.y = f2bf(acc.y * inv + bz.y);
    o.z = f2bf(acc.z * inv + bz.z);
    o.w = f2bf(acc.w * inv + bz.w);
    *(ushort4*)(z2h + (size_t)i * OUTD + l16 * 4) = o;
  }
}

// ---------------- decoder stage B ------------------------------------------
__global__ __launch_bounds__(256) void k_link(
    const float* __restrict__ u, const float* __restrict__ v,
    const int* __restrict__ eli, int EL,
    const float* __restrict__ bm1, const float* __restrict__ Wm2,
    const float* __restrict__ bm2, float* __restrict__ out) {
  int tid = threadIdx.x, lane = tid & 63, w = tid >> 6;
  int li = lane >> 4, c4 = (lane & 15) * 4;
  int l = (blockIdx.x * 4 + w) * 4 + li;
  if (l >= EL) return;
  int a = eli[l], b = eli[EL + l];
  float4 uu = *(const float4*)(u + (size_t)a * OUTD + c4);
  float4 vv = *(const float4*)(v + (size_t)b * OUTD + c4);
  float4 bb = *(const float4*)(bm1 + c4);
  float4 ww = *(const float4*)(Wm2 + c4);
  float p = fmaxf(uu.x + vv.x + bb.x, 0.f) * ww.x
          + fmaxf(uu.y + vv.y + bb.y, 0.f) * ww.y
          + fmaxf(uu.z + vv.z + bb.z, 0.f) * ww.z
          + fmaxf(uu.w + vv.w + bb.w, 0.f) * ww.w;
  RED16(p);
  if ((lane & 15) == 0) out[l] = p + bm2[0];
}

extern "C" void kernel_launch(void* const* d_in, const int* in_sizes, int n_in,
                              void* d_out, int out_size, void* d_ws, size_t ws_size,
                              hipStream_t stream) {
  const float* x     = (const float*)d_in[0];
  const int*   ei    = (const int*)d_in[1];
  const int*   eli   = (const int*)d_in[2];
  const float* W1l   = (const float*)d_in[3];
  const float* b1l   = (const float*)d_in[4];
  const float* W1r   = (const float*)d_in[5];
  const float* b1r   = (const float*)d_in[6];
  const float* att1  = (const float*)d_in[7];
  const float* bias1 = (const float*)d_in[8];
  const float* W2l   = (const float*)d_in[9];
  const float* b2l   = (const float*)d_in[10];
  const float* W2r   = (const float*)d_in[11];
  const float* b2r   = (const float*)d_in[12];
  const float* att2  = (const float*)d_in[13];
  const float* bias2 = (const float*)d_in[14];
  const float* Wm1   = (const float*)d_in[15];
  const float* bm1   = (const float*)d_in[16];
  const float* Wm2   = (const float*)d_in[17];
  const float* bm2   = (const float*)d_in[18];

  int N = in_sizes[0] / IN_DIM;   // 50000
  int E = in_sizes[1] / 2;        // 800000
  int EL = in_sizes[2] / 2;       // 200000

  // ---- workspace layout (bytes) ----
  // [0, 25.6M)      xlh bf16        (layer2: xl2h bf16 @0, xr2h bf16 @12.8M)
  // [25.6M, 38.4M)  xb bf16         (layer2: z2h bf16 @25.6M after gemm1 dead)
  // [38.4M..39.3M)  Wt, Wt2, Wuv
  // [51.2M, 76.8M)  xrh bf16        (decoder: u @51.2M, v @64M)
  // [76.8M, 102.4M) zh bf16
  // [102.4M..]      row_start | csr_src @103.0M | blk_sum @106.3M
  //                 rank @106.4M | cnt4(4N) @109.7M | lps @110.6M
  char* ws = (char*)d_ws;
  unsigned short* xlh  = (unsigned short*)(ws);
  unsigned short* xb   = (unsigned short*)(ws + 25600000);
  unsigned short* Wt   = (unsigned short*)(ws + 38400000);
  unsigned short* Wt2  = (unsigned short*)(ws + 39000000);
  unsigned short* Wuv  = (unsigned short*)(ws + 39200000);
  unsigned short* xrh  = (unsigned short*)(ws + 51200000);
  unsigned short* zh   = (unsigned short*)(ws + 76800000);
  int*   row_start = (int*)(ws + 102400000);
  int*   csr_src   = (int*)(ws + 103000000);
  int*   blk_sum   = (int*)(ws + 106300000);
  int*   rank      = (int*)(ws + 106400000);
  int*   cnt4      = (int*)(ws + 109700000);
  int*   lps       = (int*)(ws + 110600000);
  unsigned short* xl2h = (unsigned short*)(ws);
  unsigned short* xr2h = (unsigned short*)(ws + 12800000);
  unsigned short* z2h  = (unsigned short*)(ws + 25600000);
  float* u_buf     = (float*)(ws + 51200000);
  float* v_buf     = (float*)(ws + 64000000);

  int nblk = (N + 1023) / 1024;   // 49 (<=64 required by k_scan2)
  int NX8 = N * IN_DIM / 8;       // 800000
  int gx = (N + 63) / 64;         // 782
  int per = gx * 256;             // 200192 edges per y-copy
  int cvt_total = NX8 + 4 * N;    // covers cnt4 zero + all weights

  // ---- conversions (+cnt4 zero); gemm1 fuses y-privatized rank-hist ----
  k_cvt_all<<<(cvt_total + 255) / 256, 256, 0, stream>>>(
      x, xb, NX8, W1l, W1r, W2l, W2r, Wm1, Wt, Wt2, Wuv, cnt4, N);
  {
    dim3 g1(gx, 4);
    k_gemm1_mfma<<<g1, 256, 0, stream>>>(xb, Wt, b1l, b1r, xlh, xrh,
                                         ei, E, cnt4, rank, N);
  }
  k_scan1<<<nblk, 256, 0, stream>>>(cnt4, N, lps, blk_sum);
  k_scan2<<<1, 64, 0, stream>>>(blk_sum, nblk);
  k_scan3<<<(N + 255) / 256, 256, 0, stream>>>(lps, blk_sum, N, E,
                                               row_start, cnt4);
  k_scatter<<<(E / 4 + 255) / 256, 256, 0, stream>>>(ei, E, per, cnt4, rank,
                                                     csr_src, N);

  // ---- layer 1 (fused) ----
  k_fused1<<<(N + 3) / 4, 256, 0, stream>>>(xlh, xrh, row_start, csr_src,
                                            att1, bias1, zh, N);
  // ---- layer 2 ----
  k_gemm2_mfma<<<(N + 63) / 64, 256, 0, stream>>>(zh, Wt2, b2l, b2r,
                                                  xl2h, xr2h, N);
  k_fused2<<<(N + 3) / 4, 256, 0, stream>>>(xl2h, xr2h, row_start, csr_src,
                                            att2, bias2, z2h, N);
  // ---- decoder ----
  {
    dim3 g3((N + 63) / 64, 2);
    k_uv_mfma<<<g3, 256, 0, stream>>>(z2h, Wuv, u_buf, v_buf, N);
  }
  k_link<<<(EL + 15) / 16, 256, 0, stream>>>(u_buf, v_buf, eli, EL,
                                             bm1, Wm2, bm2, (float*)d_out);
}

// Round 30
// 250.629 us; speedup vs baseline: 1.0419x; 1.0341x over previous
//
#include <hip/hip_runtime.h>
#include <hip/hip_bf16.h>

#define IN_DIM 128
#define HID    64
#define NH     4
#define F1     256   // NH*HID
#define OUTD   64
#define NEG    0.2f
#define LOG2E  1.44269504088896f

#define EXP2F(x) __builtin_amdgcn_exp2f(x)

typedef __attribute__((ext_vector_type(8))) short bf16x8;
typedef __attribute__((ext_vector_type(4))) float f32x4;
typedef __attribute__((ext_vector_type(4))) unsigned short u16x4;

__device__ __forceinline__ float bf2f(unsigned short h) {
  return __uint_as_float((unsigned)h << 16);
}
__device__ __forceinline__ unsigned short f2bf(float f) {
  unsigned u = __float_as_uint(f);
  u += 0x7fffu + ((u >> 16) & 1u);   // RTNE
  return (unsigned short)(u >> 16);
}
__device__ __forceinline__ bf16x8 f2bf8(const float* p) {
  float4 lo = *(const float4*)p;
  float4 hi = *(const float4*)(p + 4);
  bf16x8 r;
  r[0] = (short)f2bf(lo.x); r[1] = (short)f2bf(lo.y);
  r[2] = (short)f2bf(lo.z); r[3] = (short)f2bf(lo.w);
  r[4] = (short)f2bf(hi.x); r[5] = (short)f2bf(hi.y);
  r[6] = (short)f2bf(hi.z); r[7] = (short)f2bf(hi.w);
  return r;
}

// ---------------- fused conversions: x->bf16, weights, cnt4 zero ------------
__global__ __launch_bounds__(256) void k_cvt_all(
    const float* __restrict__ x, unsigned short* __restrict__ xb, int NX8,
    const float* __restrict__ W1l, const float* __restrict__ W1r,
    const float* __restrict__ W2l, const float* __restrict__ W2r,
    const float* __restrict__ Wm1,
    unsigned short* __restrict__ Wt, unsigned short* __restrict__ Wt2,
    unsigned short* __restrict__ Wuv, int* __restrict__ cnt4, int N) {
  int idx = blockIdx.x * 256 + threadIdx.x;
  if (idx < NX8) {
    bf16x8 r = f2bf8(x + (size_t)idx * 8);
    *(bf16x8*)(xb + (size_t)idx * 8) = r;
    return;
  }
  int j0 = idx - NX8;
  if (j0 < 4 * N) cnt4[j0] = 0;
  if (j0 < 512 * IN_DIM) {
    int c = j0 >> 7, k = j0 & 127;
    float v = (c < F1) ? W1l[k * F1 + c] : W1r[k * F1 + (c - F1)];
    Wt[j0] = f2bf(v);
  } else if (j0 < 512 * IN_DIM + 128 * F1) {
    int j = j0 - 512 * IN_DIM;
    int c = j >> 8, k = j & 255;
    float v = (c < OUTD) ? W2l[k * OUTD + c] : W2r[k * OUTD + (c - OUTD)];
    Wt2[j] = f2bf(v);
  } else if (j0 < 512 * IN_DIM + 128 * F1 + 128 * OUTD) {
    int j = j0 - 512 * IN_DIM - 128 * F1;
    int c = j >> 6, k = j & 63;
    float v = (c < OUTD) ? Wm1[k * OUTD + c] : Wm1[(64 + k) * OUTD + (c - OUTD)];
    Wuv[j] = f2bf(v);
  }
}

// ---------------- layer-1 GEMM via MFMA, LDS-staged weights + rank-hist -----
// grid ((N+63)/64, 4). Block stages its 32KB weight slice in LDS (padded
// stride 132 shorts -> <=2-way banks); hist atomic overlaps the barrier.
#define LWS 132
__global__ __launch_bounds__(256) void k_gemm1_mfma(
    const unsigned short* __restrict__ xb, const unsigned short* __restrict__ Wt,
    const float* __restrict__ bl, const float* __restrict__ br,
    unsigned short* __restrict__ xlh, unsigned short* __restrict__ xrh,
    const int* __restrict__ ei, int E, int* __restrict__ cnt4,
    int* __restrict__ rank, int N) {
  __shared__ __align__(16) unsigned short lw[128 * LWS];
  int tid = threadIdx.x, lane = tid & 63, w = tid >> 6;
  int node0 = blockIdx.x * 64 + w * 16;
  int colbase = blockIdx.y * 128;
  int l16 = lane & 15, khi = lane >> 4;
  int koff = khi * 8;
  // stage the 128-col x 128-k weight slice (2048 chunks of 8 shorts)
  {
    const unsigned short* src = Wt + (size_t)colbase * IN_DIM;
#pragma unroll
    for (int it = 0; it < 8; it++) {
      int c = it * 256 + tid;
      int col = c >> 4, k8 = (c & 15) * 8;
      *(bf16x8*)(&lw[col * LWS + k8]) = *(const bf16x8*)(src + col * IN_DIM + k8);
    }
  }
  // b-frags from global (independent of staging)
  int arow = node0 + l16; if (arow >= N) arow = N - 1;
  const unsigned short* ap = xb + (size_t)arow * IN_DIM + koff;
  bf16x8 b0 = *(const bf16x8*)(ap);
  bf16x8 b1 = *(const bf16x8*)(ap + 32);
  bf16x8 b2 = *(const bf16x8*)(ap + 64);
  bf16x8 b3 = *(const bf16x8*)(ap + 96);
  // fused histogram: overlapped with the staging barrier
  {
    int gid = blockIdx.y * gridDim.x + blockIdx.x;
    int e = gid * 256 + tid;
    if (e < E) {
      int d = ei[E + e];
      rank[e] = atomicAdd(&cnt4[blockIdx.y * N + d], 1);
    }
  }
  __syncthreads();
  int node = node0 + l16;
  bool nok = node < N;
  bool isL = (colbase < F1);
  unsigned short* dst = isL ? xlh : xrh;
  const float* bias = isL ? bl : br;
  int cofs = isL ? colbase : (colbase - F1);
#pragma unroll
  for (int cp = 0; cp < 4; cp++) {
    int ct0 = cp * 2, ct1 = cp * 2 + 1;
    const unsigned short* wp0 = &lw[(ct0 * 16 + l16) * LWS + koff];
    const unsigned short* wp1 = &lw[(ct1 * 16 + l16) * LWS + koff];
    f32x4 a0 = {0.f, 0.f, 0.f, 0.f};
    f32x4 a1 = {0.f, 0.f, 0.f, 0.f};
    a0 = __builtin_amdgcn_mfma_f32_16x16x32_bf16(*(const bf16x8*)(wp0), b0, a0, 0, 0, 0);
    a1 = __builtin_amdgcn_mfma_f32_16x16x32_bf16(*(const bf16x8*)(wp1), b0, a1, 0, 0, 0);
    a0 = __builtin_amdgcn_mfma_f32_16x16x32_bf16(*(const bf16x8*)(wp0 + 32), b1, a0, 0, 0, 0);
    a1 = __builtin_amdgcn_mfma_f32_16x16x32_bf16(*(const bf16x8*)(wp1 + 32), b1, a1, 0, 0, 0);
    a0 = __builtin_amdgcn_mfma_f32_16x16x32_bf16(*(const bf16x8*)(wp0 + 64), b2, a0, 0, 0, 0);
    a1 = __builtin_amdgcn_mfma_f32_16x16x32_bf16(*(const bf16x8*)(wp1 + 64), b2, a1, 0, 0, 0);
    a0 = __builtin_amdgcn_mfma_f32_16x16x32_bf16(*(const bf16x8*)(wp0 + 96), b3, a0, 0, 0, 0);
    a1 = __builtin_amdgcn_mfma_f32_16x16x32_bf16(*(const bf16x8*)(wp1 + 96), b3, a1, 0, 0, 0);
    int lc0 = ct0 * 16 + khi * 4;
    int lc1 = ct1 * 16 + khi * 4;
    float4 bb0 = *(const float4*)(bias + cofs + lc0);
    float4 bb1 = *(const float4*)(bias + cofs + lc1);
    if (nok) {
      u16x4 o0, o1;
      o0[0] = f2bf(a0[0] + bb0.x); o0[1] = f2bf(a0[1] + bb0.y);
      o0[2] = f2bf(a0[2] + bb0.z); o0[3] = f2bf(a0[3] + bb0.w);
      o1[0] = f2bf(a1[0] + bb1.x); o1[1] = f2bf(a1[1] + bb1.y);
      o1[2] = f2bf(a1[2] + bb1.z); o1[3] = f2bf(a1[3] + bb1.w);
      __builtin_nontemporal_store(o0, (u16x4*)(dst + (size_t)node * F1 + cofs + lc0));
      __builtin_nontemporal_store(o1, (u16x4*)(dst + (size_t)node * F1 + cofs + lc1));
    }
  }
}

// ---------------- layer-2 GEMM via MFMA: zh bf16 in, both outs bf16 ---------
__global__ __launch_bounds__(256) void k_gemm2_mfma(
    const unsigned short* __restrict__ zh, const unsigned short* __restrict__ Wt2,
    const float* __restrict__ bl, const float* __restrict__ br,
    unsigned short* __restrict__ xl2h, unsigned short* __restrict__ xr2h, int N) {
  int tid = threadIdx.x, lane = tid & 63, w = tid >> 6;
  int node0 = blockIdx.x * 64 + w * 16;
  int l16 = lane & 15, khi = lane >> 4;
  int koff = khi * 8;
  int arow = node0 + l16; if (arow >= N) arow = N - 1;
  const unsigned short* zp = zh + (size_t)arow * F1 + koff;
  bf16x8 bfr[8];
#pragma unroll
  for (int t = 0; t < 8; t++) bfr[t] = *(const bf16x8*)(zp + 32 * t);
  int node = node0 + l16;
  bool nok = node < N;
#pragma unroll
  for (int half = 0; half < 2; half++) {
    const unsigned short* Wbase = Wt2 + (size_t)half * OUTD * F1;
    unsigned short* dst = half ? xr2h : xl2h;
    const float* bias = half ? br : bl;
#pragma unroll
    for (int ct = 0; ct < 4; ct++) {
      int wrow = ct * 16 + l16;
      const unsigned short* wp = Wbase + (size_t)wrow * F1 + koff;
      f32x4 acc = {0.f, 0.f, 0.f, 0.f};
#pragma unroll
      for (int t = 0; t < 8; t++)
        acc = __builtin_amdgcn_mfma_f32_16x16x32_bf16(
            *(const bf16x8*)(wp + 32 * t), bfr[t], acc, 0, 0, 0);
      int cbase = ct * 16 + khi * 4;
      float4 bb = *(const float4*)(bias + cbase);
      if (nok) {
        ushort4 o;
        o.x = f2bf(acc[0] + bb.x); o.y = f2bf(acc[1] + bb.y);
        o.z = f2bf(acc[2] + bb.z); o.w = f2bf(acc[3] + bb.w);
        *(ushort4*)(dst + (size_t)node * OUTD + cbase) = o;
      }
    }
  }
}

// ---------------- decoder uv GEMM via MFMA: z2h bf16 in ---------------------
__global__ __launch_bounds__(256) void k_uv_mfma(
    const unsigned short* __restrict__ z2h, const unsigned short* __restrict__ Wuv,
    float* __restrict__ u, float* __restrict__ v, int N) {
  int tid = threadIdx.x, lane = tid & 63, w = tid >> 6;
  int node0 = blockIdx.x * 64 + w * 16;
  int half = blockIdx.y;
  int l16 = lane & 15, khi = lane >> 4;
  int koff = khi * 8;
  int arow = node0 + l16; if (arow >= N) arow = N - 1;
  const unsigned short* zp = z2h + (size_t)arow * OUTD + koff;
  bf16x8 b0 = *(const bf16x8*)(zp);
  bf16x8 b1 = *(const bf16x8*)(zp + 32);
  const unsigned short* Wbase = Wuv + (size_t)half * OUTD * OUTD;
  float* dst = half ? v : u;
  int node = node0 + l16;
  bool nok = node < N;
#pragma unroll
  for (int ct = 0; ct < 4; ct++) {
    int wrow = ct * 16 + l16;
    const unsigned short* wp = Wbase + (size_t)wrow * OUTD + koff;
    f32x4 acc = {0.f, 0.f, 0.f, 0.f};
    acc = __builtin_amdgcn_mfma_f32_16x16x32_bf16(*(const bf16x8*)(wp), b0, acc, 0, 0, 0);
    acc = __builtin_amdgcn_mfma_f32_16x16x32_bf16(*(const bf16x8*)(wp + 32), b1, acc, 0, 0, 0);
    int cbase = ct * 16 + khi * 4;
    if (nok) {
      float4 o;
      o.x = acc[0]; o.y = acc[1]; o.z = acc[2]; o.w = acc[3];
      *(float4*)(dst + (size_t)node * OUTD + cbase) = o;
    }
  }
}

// ---------------- CSR scan over 4 privatized copies -------------------------
__global__ __launch_bounds__(256) void k_scan1(
    const int* __restrict__ cnt4, int N, int* __restrict__ lps,
    int* __restrict__ blk_sum) {
  int t = threadIdx.x, lane = t & 63, wid = t >> 6;
  int base = blockIdx.x * 1024 + t * 4;
  int4 v = {0, 0, 0, 0};
#pragma unroll
  for (int y = 0; y < 4; y++) {
    const int* c = cnt4 + (size_t)y * N;
    if (base + 3 < N) {
      int4 cy = *(const int4*)(c + base);
      v.x += cy.x; v.y += cy.y; v.z += cy.z; v.w += cy.w;
    } else {
      if (base + 0 < N) v.x += c[base + 0];
      if (base + 1 < N) v.y += c[base + 1];
      if (base + 2 < N) v.z += c[base + 2];
      if (base + 3 < N) v.w += c[base + 3];
    }
  }
  int s = v.x + v.y + v.z + v.w;
  int inc = s;
#pragma unroll
  for (int off = 1; off < 64; off <<= 1) {
    int u = __shfl_up(inc, off, 64);
    if (lane >= off) inc += u;
  }
  __shared__ int wsum[4];
  if (lane == 63) wsum[wid] = inc;
  __syncthreads();
  int wofs = 0;
#pragma unroll
  for (int q = 0; q < 4; q++) if (q < wid) wofs += wsum[q];
  int excl = wofs + inc - s;
  int4 o;
  o.x = excl; o.y = excl + v.x; o.z = o.y + v.y; o.w = o.z + v.z;
  if (base + 3 < N) {
    *(int4*)(lps + base) = o;
  } else {
    if (base + 0 < N) lps[base + 0] = o.x;
    if (base + 1 < N) lps[base + 1] = o.y;
    if (base + 2 < N) lps[base + 2] = o.z;
    if (base + 3 < N) lps[base + 3] = o.w;
  }
  if (t == 255) blk_sum[blockIdx.x] = wofs + inc;
}

__global__ void k_scan2(int* __restrict__ blk, int nblk) {
  int lane = threadIdx.x;
  int v = (lane < nblk) ? blk[lane] : 0;
  int inc = v;
#pragma unroll
  for (int off = 1; off < 64; off <<= 1) {
    int u = __shfl_up(inc, off, 64);
    if (lane >= off) inc += u;
  }
  if (lane < nblk) blk[lane] = inc - v;
}

__global__ __launch_bounds__(256) void k_scan3(
    const int* __restrict__ lps, const int* __restrict__ blk_sum,
    int N, int E, int* __restrict__ row_start, int* __restrict__ cnt4) {
  int i = blockIdx.x * 256 + threadIdx.x;
  if (i < N) {
    int p = lps[i] + blk_sum[i >> 10];
    row_start[i] = p;
    int c0 = cnt4[i];
    int c1 = cnt4[(size_t)N + i];
    int c2 = cnt4[(size_t)2 * N + i];
    cnt4[i] = p;
    cnt4[(size_t)N + i] = p + c0;
    cnt4[(size_t)2 * N + i] = p + c0 + c1;
    cnt4[(size_t)3 * N + i] = p + c0 + c1 + c2;
  }
  if (i == 0) row_start[N] = E;
}

__global__ __launch_bounds__(256) void k_scatter(
    const int* __restrict__ ei, int E, int per, const int* __restrict__ cnt4,
    const int* __restrict__ rank, int* __restrict__ csr_src, int N) {
  int e4 = (blockIdx.x * 256 + threadIdx.x) * 4;
  if (e4 + 3 < E) {
    int4 s = *(const int4*)(ei + e4);
    int4 d = *(const int4*)(ei + E + e4);
    int4 r = *(const int4*)(rank + e4);
    int y0 = e4 / per, y1 = (e4 + 1) / per;
    int y2 = (e4 + 2) / per, y3 = (e4 + 3) / per;
    csr_src[cnt4[(size_t)y0 * N + d.x] + r.x] = s.x;
    csr_src[cnt4[(size_t)y1 * N + d.y] + r.y] = s.y;
    csr_src[cnt4[(size_t)y2 * N + d.z] + r.z] = s.z;
    csr_src[cnt4[(size_t)y3 * N + d.w] + r.w] = s.w;
  } else {
    for (int e = e4; e < E; e++)
      csr_src[cnt4[(size_t)(e / per) * N + ei[E + e]] + rank[e]] = ei[e];
  }
}

// ---------------- DPP 16-lane butterfly sum ---------------------------------
#define DPP_ADD(p, ctrl)                                                     \
  p += __int_as_float(__builtin_amdgcn_update_dpp(                           \
      0, __float_as_int(p), ctrl, 0xF, 0xF, true))
#define RED16(p)  { DPP_ADD(p, 0xB1); DPP_ADD(p, 0x4E);                      \
                    DPP_ADD(p, 0x124); DPP_ADD(p, 0x128); }

#define BF4(dst, h)                                \
  dst.x = bf2f(h.x); dst.y = bf2f(h.y);            \
  dst.z = bf2f(h.z); dst.w = bf2f(h.w);

#define DOTABS(p, xv)                                              \
  { float t;                                                       \
    t = xv.x + xri.x; p = fmaf(t, a6.x, p); p = fmaf(fabsf(t), a4b.x, p); \
    t = xv.y + xri.y; p = fmaf(t, a6.y, p); p = fmaf(fabsf(t), a4b.y, p); \
    t = xv.z + xri.z; p = fmaf(t, a6.z, p); p = fmaf(fabsf(t), a4b.z, p); \
    t = xv.w + xri.w; p = fmaf(t, a6.w, p); p = fmaf(fabsf(t), a4b.w, p); }

#define SETUP_A64(att, stride)                                     \
  float4 a6 = *(const float4*)((att) + (stride));                  \
  a6.x *= LOG2E; a6.y *= LOG2E; a6.z *= LOG2E; a6.w *= LOG2E;      \
  float4 a4b;                                                      \
  a4b.x = 0.4f * a6.x; a4b.y = 0.4f * a6.y;                        \
  a4b.z = 0.4f * a6.z; a4b.w = 0.4f * a6.w;                        \
  a6.x *= 0.6f; a6.y *= 0.6f; a6.z *= 0.6f; a6.w *= 0.6f;

// ---------------- fused layer-1: bf16 in/out --------------------------------
__global__ __launch_bounds__(256) void k_fused1(
    const unsigned short* __restrict__ xlh, const unsigned short* __restrict__ xrh,
    const int* __restrict__ row_start, const int* __restrict__ csr_src,
    const float* __restrict__ att, const float* __restrict__ bias,
    unsigned short* __restrict__ zh, int N) {
  int tid = threadIdx.x, lane = tid & 63, w = tid >> 6;
  int i = blockIdx.x * 4 + w;
  if (i >= N) return;
  float4 xri;
  {
    ushort4 hr = *(const ushort4*)(xrh + (size_t)i * F1 + lane * 4);
    BF4(xri, hr);
  }
  SETUP_A64(att, lane * 4);
  float den;
  float4 acc;
  {
    ushort4 hh = *(const ushort4*)(xlh + (size_t)i * F1 + lane * 4);
    float4 xs; BF4(xs, hh);
    float p = 0.f;
    DOTABS(p, xs);
    RED16(p);
    float wt = EXP2F(p);
    den = wt;
    acc.x = wt * xs.x; acc.y = wt * xs.y;
    acc.z = wt * xs.z; acc.w = wt * xs.w;
  }
  int b = row_start[i], e = row_start[i + 1];
  int k = b;
  for (; k + 3 < e; k += 4) {
    int s0 = csr_src[k], s1 = csr_src[k + 1];
    int s2 = csr_src[k + 2], s3 = csr_src[k + 3];
    ushort4 h0 = *(const ushort4*)(xlh + (size_t)s0 * F1 + lane * 4);
    ushort4 h1 = *(const ushort4*)(xlh + (size_t)s1 * F1 + lane * 4);
    ushort4 h2 = *(const ushort4*)(xlh + (size_t)s2 * F1 + lane * 4);
    ushort4 h3 = *(const ushort4*)(xlh + (size_t)s3 * F1 + lane * 4);
    float4 x0, x1, x2, x3;
    BF4(x0, h0); BF4(x1, h1); BF4(x2, h2); BF4(x3, h3);
    float p0 = 0.f, p1 = 0.f, p2 = 0.f, p3 = 0.f;
    DOTABS(p0, x0); DOTABS(p1, x1); DOTABS(p2, x2); DOTABS(p3, x3);
    RED16(p0); RED16(p1); RED16(p2); RED16(p3);
    float w0 = EXP2F(p0), w1 = EXP2F(p1);
    float w2 = EXP2F(p2), w3 = EXP2F(p3);
    den += (w0 + w1) + (w2 + w3);
    acc.x += w0 * x0.x + w1 * x1.x + w2 * x2.x + w3 * x3.x;
    acc.y += w0 * x0.y + w1 * x1.y + w2 * x2.y + w3 * x3.y;
    acc.z += w0 * x0.z + w1 * x1.z + w2 * x2.z + w3 * x3.z;
    acc.w += w0 * x0.w + w1 * x1.w + w2 * x2.w + w3 * x3.w;
  }
  for (; k < e; k++) {
    int s = csr_src[k];
    ushort4 hh = *(const ushort4*)(xlh + (size_t)s * F1 + lane * 4);
    float4 xs;
    BF4(xs, hh);
    float p = 0.f;
    DOTABS(p, xs);
    RED16(p);
    float wt = EXP2F(p);
    den += wt;
    acc.x += wt * xs.x;
    acc.y += wt * xs.y;
    acc.z += wt * xs.z;
    acc.w += wt * xs.w;
  }
  float inv = 1.f / den;
  float4 bz = *(const float4*)(bias + lane * 4);
  ushort4 o;
  o.x = f2bf(fmaxf(acc.x * inv + bz.x, 0.f));
  o.y = f2bf(fmaxf(acc.y * inv + bz.y, 0.f));
  o.z = f2bf(fmaxf(acc.z * inv + bz.z, 0.f));
  o.w = f2bf(fmaxf(acc.w * inv + bz.w, 0.f));
  *(ushort4*)(zh + (size_t)i * F1 + lane * 4) = o;
}

// ---------------- fused layer-2: 4x16 groups, bf16 in/out -------------------
__global__ __launch_bounds__(256) void k_fused2(
    const unsigned short* __restrict__ xlh, const unsigned short* __restrict__ xrh2,
    const int* __restrict__ row_start, const int* __restrict__ csr_src,
    const float* __restrict__ att, const float* __restrict__ bias,
    unsigned short* __restrict__ z2h, int N) {
  int tid = threadIdx.x, lane = tid & 63, w = tid >> 6;
  int i = blockIdx.x * 4 + w;
  if (i >= N) return;
  int g = lane >> 4, l16 = lane & 15;
  float4 xri;
  {
    ushort4 hr = *(const ushort4*)(xrh2 + (size_t)i * OUTD + l16 * 4);
    BF4(xri, hr);
  }
  SETUP_A64(att, l16 * 4);
  float den = 0.f;
  float4 acc = {0.f, 0.f, 0.f, 0.f};
  if (g == 0) {
    ushort4 hh = *(const ushort4*)(xlh + (size_t)i * OUTD + l16 * 4);
    float4 xs; BF4(xs, hh);
    float p = 0.f;
    DOTABS(p, xs);
    RED16(p);
    float wt = EXP2F(p);
    den = wt;
    acc.x = wt * xs.x; acc.y = wt * xs.y;
    acc.z = wt * xs.z; acc.w = wt * xs.w;
  }
  int b = row_start[i], e = row_start[i + 1];
  int k = b;
  for (; k + 15 < e; k += 16) {
    int ea = k + g, eb = k + 4 + g, ec = k + 8 + g, ed = k + 12 + g;
    int sa = csr_src[ea], sb = csr_src[eb], sc = csr_src[ec], sd = csr_src[ed];
    ushort4 ha = *(const ushort4*)(xlh + (size_t)sa * OUTD + l16 * 4);
    ushort4 hb = *(const ushort4*)(xlh + (size_t)sb * OUTD + l16 * 4);
    ushort4 hc = *(const ushort4*)(xlh + (size_t)sc * OUTD + l16 * 4);
    ushort4 hd = *(const ushort4*)(xlh + (size_t)sd * OUTD + l16 * 4);
    float4 xa, xb, xc, xd;
    BF4(xa, ha); BF4(xb, hb); BF4(xc, hc); BF4(xd, hd);
    float pa = 0.f, pb = 0.f, pc = 0.f, pd = 0.f;
    DOTABS(pa, xa); DOTABS(pb, xb); DOTABS(pc, xc); DOTABS(pd, xd);
    RED16(pa); RED16(pb); RED16(pc); RED16(pd);
    float wa = EXP2F(pa), wb = EXP2F(pb), wc = EXP2F(pc), wd = EXP2F(pd);
    den += (wa + wb) + (wc + wd);
    acc.x += (wa * xa.x + wb * xb.x) + (wc * xc.x + wd * xd.x);
    acc.y += (wa * xa.y + wb * xb.y) + (wc * xc.y + wd * xd.y);
    acc.z += (wa * xa.z + wb * xb.z) + (wc * xc.z + wd * xd.z);
    acc.w += (wa * xa.w + wb * xb.w) + (wc * xc.w + wd * xd.w);
  }
  for (; k < e; k += 8) {
    int ea = k + g, eb = k + 4 + g;
    int sa = csr_src[ea < e ? ea : (e - 1)];
    int sb = csr_src[eb < e ? eb : (e - 1)];
    ushort4 ha = *(const ushort4*)(xlh + (size_t)sa * OUTD + l16 * 4);
    ushort4 hb = *(const ushort4*)(xlh + (size_t)sb * OUTD + l16 * 4);
    float4 xa, xb;
    BF4(xa, ha); BF4(xb, hb);
    float pa = 0.f, pb = 0.f;
    DOTABS(pa, xa); DOTABS(pb, xb);
    RED16(pa); RED16(pb);
    float wa = (ea < e) ? EXP2F(pa) : 0.f;
    float wb = (eb < e) ? EXP2F(pb) : 0.f;
    den += wa + wb;
    acc.x += wa * xa.x + wb * xb.x;
    acc.y += wa * xa.y + wb * xb.y;
    acc.z += wa * xa.z + wb * xb.z;
    acc.w += wa * xa.w + wb * xb.w;
  }
#pragma unroll
  for (int off = 16; off <= 32; off <<= 1) {
    den   += __shfl_xor(den, off, 64);
    acc.x += __shfl_xor(acc.x, off, 64);
    acc.y += __shfl_xor(acc.y, off, 64);
    acc.z += __shfl_xor(acc.z, off, 64);
    acc.w += __shfl_xor(acc.w, off, 64);
  }
  if (g == 0) {
    float inv = 1.f / den;
    float4 bz = *(const float4*)(bias + l16 * 4);
    ushort4 o;
    o.x = f2bf(acc.x * inv + bz.x);
    o.y = f2bf(acc.y * inv + bz.y);
    o.z = f2bf(acc.z * inv + bz.z);
    o.w = f2bf(acc.w * inv + bz.w);
    *(ushort4*)(z2h + (size_t)i * OUTD + l16 * 4) = o;
  }
}

// ---------------- decoder stage B ------------------------------------------
__global__ __launch_bounds__(256) void k_link(
    const float* __restrict__ u, const float* __restrict__ v,
    const int* __restrict__ eli, int EL,
    const float* __restrict__ bm1, const float* __restrict__ Wm2,
    const float* __restrict__ bm2, float* __restrict__ out) {
  int tid = threadIdx.x, lane = tid & 63, w = tid >> 6;
  int li = lane >> 4, c4 = (lane & 15) * 4;
  int l = (blockIdx.x * 4 + w) * 4 + li;
  if (l >= EL) return;
  int a = eli[l], b = eli[EL + l];
  float4 uu = *(const float4*)(u + (size_t)a * OUTD + c4);
  float4 vv = *(const float4*)(v + (size_t)b * OUTD + c4);
  float4 bb = *(const float4*)(bm1 + c4);
  float4 ww = *(const float4*)(Wm2 + c4);
  float p = fmaxf(uu.x + vv.x + bb.x, 0.f) * ww.x
          + fmaxf(uu.y + vv.y + bb.y, 0.f) * ww.y
          + fmaxf(uu.z + vv.z + bb.z, 0.f) * ww.z
          + fmaxf(uu.w + vv.w + bb.w, 0.f) * ww.w;
  RED16(p);
  if ((lane & 15) == 0) out[l] = p + bm2[0];
}

extern "C" void kernel_launch(void* const* d_in, const int* in_sizes, int n_in,
                              void* d_out, int out_size, void* d_ws, size_t ws_size,
                              hipStream_t stream) {
  const float* x     = (const float*)d_in[0];
  const int*   ei    = (const int*)d_in[1];
  const int*   eli   = (const int*)d_in[2];
  const float* W1l   = (const float*)d_in[3];
  const float* b1l   = (const float*)d_in[4];
  const float* W1r   = (const float*)d_in[5];
  const float* b1r   = (const float*)d_in[6];
  const float* att1  = (const float*)d_in[7];
  const float* bias1 = (const float*)d_in[8];
  const float* W2l   = (const float*)d_in[9];
  const float* b2l   = (const float*)d_in[10];
  const float* W2r   = (const float*)d_in[11];
  const float* b2r   = (const float*)d_in[12];
  const float* att2  = (const float*)d_in[13];
  const float* bias2 = (const float*)d_in[14];
  const float* Wm1   = (const float*)d_in[15];
  const float* bm1   = (const float*)d_in[16];
  const float* Wm2   = (const float*)d_in[17];
  const float* bm2   = (const float*)d_in[18];

  int N = in_sizes[0] / IN_DIM;   // 50000
  int E = in_sizes[1] / 2;        // 800000
  int EL = in_sizes[2] / 2;       // 200000

  char* ws = (char*)d_ws;
  unsigned short* xlh  = (unsigned short*)(ws);
  unsigned short* xb   = (unsigned short*)(ws + 25600000);
  unsigned short* Wt   = (unsigned short*)(ws + 38400000);
  unsigned short* Wt2  = (unsigned short*)(ws + 39000000);
  unsigned short* Wuv  = (unsigned short*)(ws + 39200000);
  unsigned short* xrh  = (unsigned short*)(ws + 51200000);
  unsigned short* zh   = (unsigned short*)(ws + 76800000);
  int*   row_start = (int*)(ws + 102400000);
  int*   csr_src   = (int*)(ws + 103000000);
  int*   blk_sum   = (int*)(ws + 106300000);
  int*   rank      = (int*)(ws + 106400000);
  int*   cnt4      = (int*)(ws + 109700000);
  int*   lps       = (int*)(ws + 110600000);
  unsigned short* xl2h = (unsigned short*)(ws);
  unsigned short* xr2h = (unsigned short*)(ws + 12800000);
  unsigned short* z2h  = (unsigned short*)(ws + 25600000);
  float* u_buf     = (float*)(ws + 51200000);
  float* v_buf     = (float*)(ws + 64000000);

  int nblk = (N + 1023) / 1024;   // 49 (<=64 required by k_scan2)
  int NX8 = N * IN_DIM / 8;       // 800000
  int gx = (N + 63) / 64;         // 782
  int per = gx * 256;             // 200192 edges per y-copy
  int cvt_total = NX8 + 4 * N;

  // ---- conversions (+cnt4 zero); gemm1 fuses y-privatized rank-hist ----
  k_cvt_all<<<(cvt_total + 255) / 256, 256, 0, stream>>>(
      x, xb, NX8, W1l, W1r, W2l, W2r, Wm1, Wt, Wt2, Wuv, cnt4, N);
  {
    dim3 g1(gx, 4);
    k_gemm1_mfma<<<g1, 256, 0, stream>>>(xb, Wt, b1l, b1r, xlh, xrh,
                                         ei, E, cnt4, rank, N);
  }
  k_scan1<<<nblk, 256, 0, stream>>>(cnt4, N, lps, blk_sum);
  k_scan2<<<1, 64, 0, stream>>>(blk_sum, nblk);
  k_scan3<<<(N + 255) / 256, 256, 0, stream>>>(lps, blk_sum, N, E,
                                               row_start, cnt4);
  k_scatter<<<(E / 4 + 255) / 256, 256, 0, stream>>>(ei, E, per, cnt4, rank,
                                                     csr_src, N);

  // ---- layer 1 (fused) ----
  k_fused1<<<(N + 3) / 4, 256, 0, stream>>>(xlh, xrh, row_start, csr_src,
                                            att1, bias1, zh, N);
  // ---- layer 2 ----
  k_gemm2_mfma<<<(N + 63) / 64, 256, 0, stream>>>(zh, Wt2, b2l, b2r,
                                                  xl2h, xr2h, N);
  k_fused2<<<(N + 3) / 4, 256, 0, stream>>>(xl2h, xr2h, row_start, csr_src,
                                            att2, bias2, z2h, N);
  // ---- decoder ----
  {
    dim3 g3((N + 63) / 64, 2);
    k_uv_mfma<<<g3, 256, 0, stream>>>(z2h, Wuv, u_buf, v_buf, N);
  }
  k_link<<<(EL + 15) / 16, 256, 0, stream>>>(u_buf, v_buf, eli, EL,
                                             bm1, Wm2, bm2, (float*)d_out);
}